// Round 18
// baseline (323.733 us; speedup 1.0000x reference)
//
#include <hip/hip_runtime.h>
#include <stdint.h>

typedef __bf16 bf16x8 __attribute__((ext_vector_type(8)));
typedef float f32x4 __attribute__((ext_vector_type(4)));

#define LQ 1024
#define LK 1024
#define BB 8
#define DD 1024
#define HH 16
#define DK 64

__device__ __forceinline__ unsigned short f2bf(float f) {
  union { float f; unsigned u; } v; v.f = f;
  unsigned u = v.u;
  u += 0x7FFFu + ((u >> 16) & 1u);   // RNE
  return (unsigned short)(u >> 16);
}
__device__ __forceinline__ float bf2f(unsigned short u) {
  union { unsigned u; float f; } v; v.u = ((unsigned)u) << 16;
  return v.f;
}
__device__ __forceinline__ f32x4 mfma16(bf16x8 a, bf16x8 b, f32x4 c) {
  return __builtin_amdgcn_mfma_f32_16x16x32_bf16(a, b, c, 0, 0, 0);
}
// async global->LDS, 16B per lane; LDS dest is wave-uniform base + lane*16
__device__ __forceinline__ void gload_lds16(const unsigned short* g, unsigned short* l) {
  __builtin_amdgcn_global_load_lds(
      (const __attribute__((address_space(1))) void*)g,
      (__attribute__((address_space(3))) void*)l, 16, 0, 0);
}

// ---------------- fp32 -> bf16 bulk convert ----------------
__global__ __launch_bounds__(256) void cvt_k(const float* __restrict__ in,
                                             unsigned short* __restrict__ out,
                                             int n4) {
  int i = blockIdx.x * 256 + threadIdx.x;
  if (i < n4) {
    float4 v = *(const float4*)(in + (size_t)i * 4);
    uint2 o;
    o.x = f2bf(v.x) | ((unsigned)f2bf(v.y) << 16);
    o.y = f2bf(v.z) | ((unsigned)f2bf(v.w) << 16);
    *(uint2*)(out + (size_t)i * 4) = o;
  }
}

// ------------- fused weight converts (Wq | Wkv | Wo) in one launch --------
__global__ __launch_bounds__(256) void cvtW_k(const float* __restrict__ Wq,
                                              const float* __restrict__ Wkv,
                                              const float* __restrict__ Wo,
                                              unsigned short* __restrict__ oq,
                                              unsigned short* __restrict__ okv,
                                              unsigned short* __restrict__ oo) {
  int i = blockIdx.x * 256 + threadIdx.x;   // float4 index, total 1M
  const float* in;
  unsigned short* out;
  int j;
  if (i < 262144) { in = Wq; out = oq; j = i; }
  else if (i < 786432) { in = Wkv; out = okv; j = i - 262144; }
  else { in = Wo; out = oo; j = i - 786432; }
  float4 v = *(const float4*)(in + (size_t)j * 4);
  uint2 o;
  o.x = f2bf(v.x) | ((unsigned)f2bf(v.y) << 16);
  o.y = f2bf(v.z) | ((unsigned)f2bf(v.w) << 16);
  *(uint2*)(out + (size_t)j * 4) = o;
}

// ---------------- LayerNorm (row = 1024) -> bf16 ----------------
__global__ __launch_bounds__(256) void layernorm_k(const float* __restrict__ x,
                                                   const float* __restrict__ g,
                                                   const float* __restrict__ bta,
                                                   unsigned short* __restrict__ out) {
  const int row = blockIdx.x;
  const float* xr = x + (size_t)row * DD;
  const int t = threadIdx.x;
  float4 v = *(const float4*)(xr + t * 4);
  float s = v.x + v.y + v.z + v.w;
  float s2 = v.x * v.x + v.y * v.y + v.z * v.z + v.w * v.w;
  for (int off = 32; off > 0; off >>= 1) {
    s += __shfl_down(s, off);
    s2 += __shfl_down(s2, off);
  }
  __shared__ float red[8];
  int lane = t & 63, w = t >> 6;
  if (lane == 0) { red[w] = s; red[4 + w] = s2; }
  __syncthreads();
  s = red[0] + red[1] + red[2] + red[3];
  s2 = red[4] + red[5] + red[6] + red[7];
  float mu = s * (1.0f / 1024.0f);
  float var = s2 * (1.0f / 1024.0f) - mu * mu;
  float inv = rsqrtf(var + 1e-5f);
  float4 gv = *(const float4*)(g + t * 4);
  float4 bv = *(const float4*)(bta + t * 4);
  uint2 o;
  o.x = f2bf((v.x - mu) * inv * gv.x + bv.x) |
        ((unsigned)f2bf((v.y - mu) * inv * gv.y + bv.y) << 16);
  o.y = f2bf((v.z - mu) * inv * gv.z + bv.z) |
        ((unsigned)f2bf((v.w - mu) * inv * gv.w + bv.w) << 16);
  *(uint2*)(out + (size_t)row * DD + t * 4) = o;
}

// ---------------- generic C = scale * A @ B^T  (+residual) ----------------
// m97 structure: BK=64, global_load_lds width-16 staging, linear LDS tiles.
template <bool OUT_F32, bool ADD_RES>
__global__ __launch_bounds__(256) void gemm_bt_k(const unsigned short* __restrict__ A, int lda,
                                                 const unsigned short* __restrict__ B, int ldb,
                                                 void* __restrict__ Cv, int ldc,
                                                 const float* __restrict__ res,
                                                 float scale, int K) {
  __shared__ __align__(16) unsigned short As[128 * 64];
  __shared__ __align__(16) unsigned short Bs[128 * 64];
  const int t = threadIdx.x;
  const int lane = t & 63, wave = t >> 6;
  const int fr = lane & 15, fq = lane >> 4;
  const int wr = (wave >> 1) * 64, wc = (wave & 1) * 64;
  const int m0 = blockIdx.y * 128, n0 = blockIdx.x * 128;
  const int lrow = lane >> 3, lcol = (lane & 7) * 8;  // 8 rows x 64 cols per issue
  f32x4 acc[4][4] = {};
  for (int k0 = 0; k0 < K; k0 += 64) {
    __syncthreads();
#pragma unroll
    for (int i = 0; i < 4; ++i) {
      int rbase = wave * 32 + i * 8;
      int r = rbase + lrow;
      gload_lds16(A + (size_t)(m0 + r) * lda + k0 + lcol, &As[rbase * 64]);
      gload_lds16(B + (size_t)(n0 + r) * ldb + k0 + lcol, &Bs[rbase * 64]);
    }
    __syncthreads();
#pragma unroll
    for (int ks = 0; ks < 2; ++ks) {
      bf16x8 af[4], bb[4];
#pragma unroll
      for (int m = 0; m < 4; ++m)
        af[m] = *(const bf16x8*)&As[(wr + m * 16 + fr) * 64 + ks * 32 + fq * 8];
#pragma unroll
      for (int n = 0; n < 4; ++n)
        bb[n] = *(const bf16x8*)&Bs[(wc + n * 16 + fr) * 64 + ks * 32 + fq * 8];
#pragma unroll
      for (int m = 0; m < 4; ++m)
#pragma unroll
        for (int n = 0; n < 4; ++n)
          acc[m][n] = mfma16(af[m], bb[n], acc[m][n]);
    }
  }
#pragma unroll
  for (int m = 0; m < 4; ++m)
#pragma unroll
    for (int n = 0; n < 4; ++n)
#pragma unroll
      for (int i = 0; i < 4; ++i) {
        int r = m0 + wr + m * 16 + fq * 4 + i;
        int c = n0 + wc + n * 16 + fr;
        float vv = acc[m][n][i] * scale;
        if (OUT_F32) {
          float rs = ADD_RES ? res[(size_t)r * ldc + c] : 0.0f;
          __builtin_nontemporal_store(vv + rs, (float*)Cv + (size_t)r * ldc + c);
        } else {
          ((unsigned short*)Cv)[(size_t)r * ldc + c] = f2bf(vv);
        }
      }
}

// --------- V-projection GEMM with transposed scatter epilogue -------------
// C[token][dglob] -> Vt[((b*16+h)*64 + d) * 1024 + kk]
__global__ __launch_bounds__(256) void gemm_vt_k(const unsigned short* __restrict__ A, int lda,
                                                 const unsigned short* __restrict__ B, int ldb,
                                                 unsigned short* __restrict__ Vt, int K) {
  __shared__ __align__(16) unsigned short As[128 * 64];
  __shared__ __align__(16) unsigned short Bs[128 * 64];
  const int t = threadIdx.x;
  const int lane = t & 63, wave = t >> 6;
  const int fr = lane & 15, fq = lane >> 4;
  const int wr = (wave >> 1) * 64, wc = (wave & 1) * 64;
  const int m0 = blockIdx.y * 128, n0 = blockIdx.x * 128;
  const int lrow = lane >> 3, lcol = (lane & 7) * 8;
  f32x4 acc[4][4] = {};
  for (int k0 = 0; k0 < K; k0 += 64) {
    __syncthreads();
#pragma unroll
    for (int i = 0; i < 4; ++i) {
      int rbase = wave * 32 + i * 8;
      int r = rbase + lrow;
      gload_lds16(A + (size_t)(m0 + r) * lda + k0 + lcol, &As[rbase * 64]);
      gload_lds16(B + (size_t)(n0 + r) * ldb + k0 + lcol, &Bs[rbase * 64]);
    }
    __syncthreads();
#pragma unroll
    for (int ks = 0; ks < 2; ++ks) {
      bf16x8 af[4], bb[4];
#pragma unroll
      for (int m = 0; m < 4; ++m)
        af[m] = *(const bf16x8*)&As[(wr + m * 16 + fr) * 64 + ks * 32 + fq * 8];
#pragma unroll
      for (int n = 0; n < 4; ++n)
        bb[n] = *(const bf16x8*)&Bs[(wc + n * 16 + fr) * 64 + ks * 32 + fq * 8];
#pragma unroll
      for (int m = 0; m < 4; ++m)
#pragma unroll
        for (int n = 0; n < 4; ++n)
          acc[m][n] = mfma16(af[m], bb[n], acc[m][n]);
    }
  }
#pragma unroll
  for (int m = 0; m < 4; ++m)
#pragma unroll
    for (int n = 0; n < 4; ++n)
#pragma unroll
      for (int i = 0; i < 4; ++i) {
        int r = m0 + wr + m * 16 + fq * 4 + i;   // token row = kk*8 + b
        int c = n0 + wc + n * 16 + fr;           // dglob = h*64 + d
        int kk = r >> 3, b_ = r & 7, h_ = c >> 6, d_ = c & 63;
        Vt[(((size_t)(b_ * 16 + h_) * 64 + d_) << 10) + kk] = f2bf(acc[m][n][i]);
      }
}

// ---------------- fused scores+softmax+PV (two-pass flash) ----------------
// grid: 2048 blocks (1D), 256 threads / 4 waves, QBLK=64 (r16 base).
// Pass 1: T3 minimal double-buffer — stage kt+1 (async gload_lds) into the
// other K buffer WHILE computing kt; ONE barrier per kt (was 2). Mask
// double-buffered. Pass 2: identical to r16 (4 barriers/kt, aliased KVu).
// XCD-aware remap; no max-tracking; attn stores non-temporal; Ps swizzled.
__global__ __launch_bounds__(256, 2) void attn_fused_k(
    const unsigned short* __restrict__ Q,   // [token][1024], pre-scaled by 0.125*log2e
    const unsigned short* __restrict__ K,   // [token][1024]
    const unsigned short* __restrict__ Vt,  // [(b*16+h)*64 + d][1024 kk]
    const unsigned char* __restrict__ mask,
    float* __restrict__ attn,               // [bh][1024 q][1024 k]
    unsigned short* __restrict__ ctx) {     // [token][1024]
  __shared__ __align__(16) unsigned short KVu[128 * 72];  // K buf A / pass-2 K,V (aliased)
  __shared__ __align__(16) unsigned short Ksd[128 * 64];  // K buf B (pass-1 dbuf)
  __shared__ __align__(16) unsigned short Ps[64 * 128];   // P bf16, XOR-swizzled rows
  __shared__ float lrow[64];
  __shared__ float ps2[64][2], maskv2[2][128];

  const int t = threadIdx.x;
  const int lane = t & 63, wave = t >> 6;
  const int fr = lane & 15, fq = lane >> 4;
  // XCD-aware (qt, bh) assignment from linear dispatch id
  const int L = blockIdx.x;                 // 0..2047, dispatch order
  const int xcd = L & 7;
  const int idx = L >> 3;                   // 0..255
  const int bh = xcd * 16 + (idx >> 4);
  const int qt = idx & 15;                  // 16 q-tiles of 64 rows
  const int b = bh >> 4, h = bh & 15;
  const int wrk = (wave >> 1) * 64;   // k-dim strip (S^T rows)
  const int wcq = (wave & 1) * 32;    // q-dim strip (S^T cols), 32 wide
  const int w01 = wave >> 1;
  const int swz = (fr & 7) << 4;      // per-lane Ps byte swizzle (row%8 == fr%8)
  const int lrow2 = lane >> 3, lcol2 = (lane & 7) * 8;  // K stage lane coords

  // Q fragments: loop-invariant, registers (64 q rows)
  bf16x8 qf[2][2];
#pragma unroll
  for (int n = 0; n < 2; ++n)
#pragma unroll
    for (int c = 0; c < 2; ++c)
      qf[n][c] = *(const bf16x8*)(Q +
          (((size_t)(qt * 64 + wcq + n * 16 + fr) * 8 + b) << 10) + h * 64 + c * 32 + fq * 8);

  // ===== pass 1: denominator only, double-buffered K (1 barrier/kt) =======
  // prologue: stage kt=0 into buf A (KVu) + mask[0]
#pragma unroll
  for (int i = 0; i < 4; ++i) {
    int rbase = wave * 32 + i * 8;
    gload_lds16(K + (((size_t)(rbase + lrow2) * 8 + b) << 10) + h * 64 + lcol2,
                &KVu[rbase * 64]);
  }
  if (t < 128) maskv2[0][t] = mask[b * 1024 + t] ? -1.0e9f : 0.0f;
  __syncthreads();

  float s_run[2] = {0.0f, 0.0f};
  for (int kt = 0; kt < 8; ++kt) {
    const int cur = kt & 1;
    unsigned short* bufc = cur ? Ksd : KVu;
    if (kt < 7) {
      unsigned short* bufn = cur ? KVu : Ksd;
      // issue async stage of kt+1 (completes by the end-of-iter barrier)
#pragma unroll
      for (int i = 0; i < 4; ++i) {
        int rbase = wave * 32 + i * 8;
        gload_lds16(K + (((size_t)((kt + 1) * 128 + rbase + lrow2) * 8 + b) << 10) + h * 64 + lcol2,
                    &bufn[rbase * 64]);
      }
      if (t < 128) maskv2[cur ^ 1][t] = mask[b * 1024 + (kt + 1) * 128 + t] ? -1.0e9f : 0.0f;
    }
    f32x4 acc[4][2] = {};
#pragma unroll
    for (int k0 = 0; k0 < 2; ++k0) {
      bf16x8 af[4];
#pragma unroll
      for (int m = 0; m < 4; ++m)
        af[m] = *(const bf16x8*)&bufc[(wrk + m * 16 + fr) * 64 + k0 * 32 + fq * 8];
      __builtin_amdgcn_s_setprio(1);
#pragma unroll
      for (int m = 0; m < 4; ++m)
#pragma unroll
        for (int n = 0; n < 2; ++n)
          acc[m][n] = mfma16(af[m], qf[n][k0], acc[m][n]);
      __builtin_amdgcn_s_setprio(0);
    }
    float4 mk[4];
#pragma unroll
    for (int m = 0; m < 4; ++m) mk[m] = *(const float4*)&maskv2[cur][wrk + m * 16 + fq * 4];
#pragma unroll
    for (int n = 0; n < 2; ++n) {
      float s = 0.0f;
#pragma unroll
      for (int m = 0; m < 4; ++m) {
        s += __builtin_amdgcn_exp2f(acc[m][n][0] + mk[m].x);
        s += __builtin_amdgcn_exp2f(acc[m][n][1] + mk[m].y);
        s += __builtin_amdgcn_exp2f(acc[m][n][2] + mk[m].z);
        s += __builtin_amdgcn_exp2f(acc[m][n][3] + mk[m].w);
      }
      s_run[n] += s;
    }
    __syncthreads();   // drains vmcnt (stage kt+1 done) + protects bufc reuse
  }
  // final cross-lane + cross-wave denominator merge (once)
#pragma unroll
  for (int n = 0; n < 2; ++n) {
    float s = s_run[n];
    s += __shfl_xor(s, 16);
    s += __shfl_xor(s, 32);
    if (fq == 0) ps2[wcq + n * 16 + fr][w01] = s;
  }
  __syncthreads();
  if (t < 64) lrow[t] = 1.0f / (ps2[t][0] + ps2[t][1]);

  // ================= pass 2: P write + attn store + PV (r16) ==============
  const int wq = (wave >> 1) * 32, wd = (wave & 1) * 32;
  f32x4 accv[2][2] = {};
  for (int kt = 0; kt < 8; ++kt) {
    __syncthreads();
#pragma unroll
    for (int i = 0; i < 4; ++i) {
      int rbase = wave * 32 + i * 8;
      gload_lds16(K + (((size_t)(kt * 128 + rbase + lrow2) * 8 + b) << 10) + h * 64 + lcol2,
                  &KVu[rbase * 64]);
    }
    if (t < 128) maskv2[0][t] = mask[b * 1024 + kt * 128 + t] ? -1.0e9f : 0.0f;
    __syncthreads();   // drains vmcnt -> gload_lds complete
    f32x4 acc[4][2] = {};
#pragma unroll
    for (int k0 = 0; k0 < 2; ++k0) {
      bf16x8 af[4];
#pragma unroll
      for (int m = 0; m < 4; ++m)
        af[m] = *(const bf16x8*)&KVu[(wrk + m * 16 + fr) * 64 + k0 * 32 + fq * 8];
      __builtin_amdgcn_s_setprio(1);
#pragma unroll
      for (int m = 0; m < 4; ++m)
#pragma unroll
        for (int n = 0; n < 2; ++n)
          acc[m][n] = mfma16(af[m], qf[n][k0], acc[m][n]);
      __builtin_amdgcn_s_setprio(0);
    }
    float4 mk[4];
#pragma unroll
    for (int m = 0; m < 4; ++m) mk[m] = *(const float4*)&maskv2[0][wrk + m * 16 + fq * 4];
#pragma unroll
    for (int m = 0; m < 4; ++m)
#pragma unroll
      for (int n = 0; n < 2; ++n) {
        acc[m][n][0] += mk[m].x; acc[m][n][1] += mk[m].y;
        acc[m][n][2] += mk[m].z; acc[m][n][3] += mk[m].w;
      }
    float il[2];
#pragma unroll
    for (int n = 0; n < 2; ++n) il[n] = lrow[wcq + n * 16 + fr];
#pragma unroll
    for (int m = 0; m < 4; ++m) {
      int k4 = wrk + m * 16 + fq * 4;
#pragma unroll
      for (int n = 0; n < 2; ++n) {
        float p0 = __builtin_amdgcn_exp2f(acc[m][n][0]) * il[n];
        float p1 = __builtin_amdgcn_exp2f(acc[m][n][1]) * il[n];
        float p2 = __builtin_amdgcn_exp2f(acc[m][n][2]) * il[n];
        float p3 = __builtin_amdgcn_exp2f(acc[m][n][3]) * il[n];
        uint2 w;
        w.x = f2bf(p0) | ((unsigned)f2bf(p1) << 16);
        w.y = f2bf(p2) | ((unsigned)f2bf(p3) << 16);
        int row = wcq + n * 16 + fr;
        *(uint2*)((char*)Ps + row * 256 + ((k4 * 2) ^ swz)) = w;
      }
    }
    __syncthreads();
    // coalesced attn write (from Ps, non-temporal f32x4) + V^T tile load
#pragma unroll
    for (int it = 0; it < 8; ++it) {
      int idx2 = it * 256 + t;
      int row = idx2 >> 5, colb = (idx2 & 31) << 3;   // 8 bytes per lane
      uint2 d2 = *(const uint2*)((const char*)Ps + row * 256 + (colb ^ ((row & 7) << 4)));
      f32x4 o;
      o[0] = bf2f((unsigned short)(d2.x & 0xFFFF));
      o[1] = bf2f((unsigned short)(d2.x >> 16));
      o[2] = bf2f((unsigned short)(d2.y & 0xFFFF));
      o[3] = bf2f((unsigned short)(d2.y >> 16));
      __builtin_nontemporal_store(
          o, (f32x4*)(attn + ((size_t)bh * 1024 + qt * 64 + row) * 1024 + kt * 128 + (colb >> 1)));
    }
#pragma unroll
    for (int it = 0; it < 4; ++it) {
      int dd = (it * 256 + t) >> 4, k8 = ((it * 256 + t) & 15) << 3;
      *(uint4*)&KVu[dd * 136 + k8] =
          *(const uint4*)(Vt + (((size_t)(b * 16 + h) * 64 + dd) << 10) + kt * 128 + k8);
    }
    __syncthreads();
    // PV: ctx[q][d] += P[q][k] * V[k][d]
#pragma unroll
    for (int ks = 0; ks < 4; ++ks) {
      bf16x8 pa[2], vb[2];
#pragma unroll
      for (int m2 = 0; m2 < 2; ++m2) {
        int row = wq + m2 * 16 + fr;
        pa[m2] = *(const bf16x8*)((const char*)Ps + row * 256 + (((ks * 32 + fq * 8) * 2) ^ swz));
      }
#pragma unroll
      for (int n2 = 0; n2 < 2; ++n2)
        vb[n2] = *(const bf16x8*)&KVu[(wd + n2 * 16 + fr) * 136 + ks * 32 + fq * 8];
      __builtin_amdgcn_s_setprio(1);
#pragma unroll
      for (int m2 = 0; m2 < 2; ++m2)
#pragma unroll
        for (int n2 = 0; n2 < 2; ++n2)
          accv[m2][n2] = mfma16(pa[m2], vb[n2], accv[m2][n2]);
      __builtin_amdgcn_s_setprio(0);
    }
  }
  // ctx epilogue
#pragma unroll
  for (int m2 = 0; m2 < 2; ++m2)
#pragma unroll
    for (int n2 = 0; n2 < 2; ++n2)
#pragma unroll
      for (int i = 0; i < 4; ++i) {
        int qrow = qt * 64 + wq + m2 * 16 + fq * 4 + i;
        int c = h * 64 + wd + n2 * 16 + fr;
        ctx[(((size_t)qrow * 8 + b) << 10) + c] = f2bf(accv[m2][n2][i]);
      }
}

extern "C" void kernel_launch(void* const* d_in, const int* in_sizes, int n_in,
                              void* d_out, int out_size, void* d_ws, size_t ws_size,
                              hipStream_t stream) {
  const float* q = (const float*)d_in[0];
  const float* k = (const float*)d_in[1];
  const unsigned char* mask = (const unsigned char*)d_in[2];
  const float* Wq = (const float*)d_in[3];
  const float* Wkv = (const float*)d_in[4];
  const float* Wo = (const float*)d_in[5];
  const float* ln_g = (const float*)d_in[6];
  const float* ln_b = (const float*)d_in[7];

  float* out0 = (float*)d_out;                   // (1024,8,1024)
  float* attn = out0 + (size_t)LQ * BB * DD;     // (8,16,1024,1024)

  char* ws = (char*)d_ws;
  unsigned short* qn   = (unsigned short*)(ws);                        // 16 MB
  unsigned short* kbf  = (unsigned short*)(ws + ((size_t)16 << 20));   // 16 MB
  unsigned short* Qw   = (unsigned short*)(ws + ((size_t)32 << 20));   // 16 MB
  unsigned short* ctxw = (unsigned short*)(ws + ((size_t)48 << 20));   // 16 MB
  unsigned short* Kw   = (unsigned short*)(ws + ((size_t)64 << 20));   // 16 MB
  unsigned short* Vtg  = (unsigned short*)(ws + ((size_t)80 << 20));   // 16 MB
  unsigned short* Wqb  = (unsigned short*)(ws + ((size_t)96 << 20));   // 2 MB
  unsigned short* Wkvb = (unsigned short*)(ws + ((size_t)98 << 20));   // 4 MB
  unsigned short* Wob  = (unsigned short*)(ws + ((size_t)102 << 20));  // 2 MB

  cvt_k<<<8192, 256, 0, stream>>>(k, kbf, (LK * BB * DD) / 4);
  cvtW_k<<<4096, 256, 0, stream>>>(Wq, Wkv, Wo, Wqb, Wkvb, Wob);

  layernorm_k<<<LQ * BB, 256, 0, stream>>>(q, ln_g, ln_b, qn);

  // Q = qn @ Wq^T * (0.125 * log2e)  -> scores in log2 domain
  gemm_bt_k<false, false><<<dim3(8, 64), 256, 0, stream>>>(
      qn, DD, Wqb, DD, Qw, DD, nullptr, 0.18033688011112f, DD);

  // K = k @ Wk^T (first half of Wkv)
  gemm_bt_k<false, false><<<dim3(8, 64), 256, 0, stream>>>(
      kbf, DD, Wkvb, DD, Kw, DD, nullptr, 1.0f, DD);

  // V^T = transpose-scatter of k @ Wv^T (second half of Wkv)
  gemm_vt_k<<<dim3(8, 64), 256, 0, stream>>>(
      kbf, DD, Wkvb + ((size_t)1 << 20), DD, Vtg, DD);

  // fused scores+softmax+PV  (1D grid, 2048 blocks, XCD-aware remap)
  attn_fused_k<<<dim3(16 * BB * HH), 256, 0, stream>>>(Qw, Kw, Vtg, mask, attn, ctxw);

  // out = ctx @ Wo^T + residual
  gemm_bt_k<true, true><<<dim3(8, 64), 256, 0, stream>>>(
      ctxw, DD, Wob, DD, out0, DD, q, 1.0f, DD);
}

// Round 19
// 288.282 us; speedup vs baseline: 1.1230x; 1.1230x over previous
//
#include <hip/hip_runtime.h>
#include <stdint.h>

typedef __bf16 bf16x8 __attribute__((ext_vector_type(8)));
typedef float f32x4 __attribute__((ext_vector_type(4)));

#define LQ 1024
#define LK 1024
#define BB 8
#define DD 1024
#define HH 16
#define DK 64

__device__ __forceinline__ unsigned short f2bf(float f) {
  union { float f; unsigned u; } v; v.f = f;
  unsigned u = v.u;
  u += 0x7FFFu + ((u >> 16) & 1u);   // RNE
  return (unsigned short)(u >> 16);
}
__device__ __forceinline__ float bf2f(unsigned short u) {
  union { unsigned u; float f; } v; v.u = ((unsigned)u) << 16;
  return v.f;
}
__device__ __forceinline__ f32x4 mfma16(bf16x8 a, bf16x8 b, f32x4 c) {
  return __builtin_amdgcn_mfma_f32_16x16x32_bf16(a, b, c, 0, 0, 0);
}
// async global->LDS, 16B per lane; LDS dest is wave-uniform base + lane*16
__device__ __forceinline__ void gload_lds16(const unsigned short* g, unsigned short* l) {
  __builtin_amdgcn_global_load_lds(
      (const __attribute__((address_space(1))) void*)g,
      (__attribute__((address_space(3))) void*)l, 16, 0, 0);
}

// ---------------- fp32 -> bf16 bulk convert ----------------
__global__ __launch_bounds__(256) void cvt_k(const float* __restrict__ in,
                                             unsigned short* __restrict__ out,
                                             int n4) {
  int i = blockIdx.x * 256 + threadIdx.x;
  if (i < n4) {
    float4 v = *(const float4*)(in + (size_t)i * 4);
    uint2 o;
    o.x = f2bf(v.x) | ((unsigned)f2bf(v.y) << 16);
    o.y = f2bf(v.z) | ((unsigned)f2bf(v.w) << 16);
    *(uint2*)(out + (size_t)i * 4) = o;
  }
}

// ------------- fused weight converts (Wq | Wkv | Wo) in one launch --------
__global__ __launch_bounds__(256) void cvtW_k(const float* __restrict__ Wq,
                                              const float* __restrict__ Wkv,
                                              const float* __restrict__ Wo,
                                              unsigned short* __restrict__ oq,
                                              unsigned short* __restrict__ okv,
                                              unsigned short* __restrict__ oo) {
  int i = blockIdx.x * 256 + threadIdx.x;   // float4 index, total 1M
  const float* in;
  unsigned short* out;
  int j;
  if (i < 262144) { in = Wq; out = oq; j = i; }
  else if (i < 786432) { in = Wkv; out = okv; j = i - 262144; }
  else { in = Wo; out = oo; j = i - 786432; }
  float4 v = *(const float4*)(in + (size_t)j * 4);
  uint2 o;
  o.x = f2bf(v.x) | ((unsigned)f2bf(v.y) << 16);
  o.y = f2bf(v.z) | ((unsigned)f2bf(v.w) << 16);
  *(uint2*)(out + (size_t)j * 4) = o;
}

// ---------------- LayerNorm (row = 1024) -> bf16 ----------------
__global__ __launch_bounds__(256) void layernorm_k(const float* __restrict__ x,
                                                   const float* __restrict__ g,
                                                   const float* __restrict__ bta,
                                                   unsigned short* __restrict__ out) {
  const int row = blockIdx.x;
  const float* xr = x + (size_t)row * DD;
  const int t = threadIdx.x;
  float4 v = *(const float4*)(xr + t * 4);
  float s = v.x + v.y + v.z + v.w;
  float s2 = v.x * v.x + v.y * v.y + v.z * v.z + v.w * v.w;
  for (int off = 32; off > 0; off >>= 1) {
    s += __shfl_down(s, off);
    s2 += __shfl_down(s2, off);
  }
  __shared__ float red[8];
  int lane = t & 63, w = t >> 6;
  if (lane == 0) { red[w] = s; red[4 + w] = s2; }
  __syncthreads();
  s = red[0] + red[1] + red[2] + red[3];
  s2 = red[4] + red[5] + red[6] + red[7];
  float mu = s * (1.0f / 1024.0f);
  float var = s2 * (1.0f / 1024.0f) - mu * mu;
  float inv = rsqrtf(var + 1e-5f);
  float4 gv = *(const float4*)(g + t * 4);
  float4 bv = *(const float4*)(bta + t * 4);
  uint2 o;
  o.x = f2bf((v.x - mu) * inv * gv.x + bv.x) |
        ((unsigned)f2bf((v.y - mu) * inv * gv.y + bv.y) << 16);
  o.y = f2bf((v.z - mu) * inv * gv.z + bv.z) |
        ((unsigned)f2bf((v.w - mu) * inv * gv.w + bv.w) << 16);
  *(uint2*)(out + (size_t)row * DD + t * 4) = o;
}

// ---------------- generic C = scale * A @ B^T  (+residual) ----------------
// m97 structure: BK=64, global_load_lds width-16 staging, linear LDS tiles.
template <bool OUT_F32, bool ADD_RES>
__global__ __launch_bounds__(256) void gemm_bt_k(const unsigned short* __restrict__ A, int lda,
                                                 const unsigned short* __restrict__ B, int ldb,
                                                 void* __restrict__ Cv, int ldc,
                                                 const float* __restrict__ res,
                                                 float scale, int K) {
  __shared__ __align__(16) unsigned short As[128 * 64];
  __shared__ __align__(16) unsigned short Bs[128 * 64];
  const int t = threadIdx.x;
  const int lane = t & 63, wave = t >> 6;
  const int fr = lane & 15, fq = lane >> 4;
  const int wr = (wave >> 1) * 64, wc = (wave & 1) * 64;
  const int m0 = blockIdx.y * 128, n0 = blockIdx.x * 128;
  const int lrow = lane >> 3, lcol = (lane & 7) * 8;  // 8 rows x 64 cols per issue
  f32x4 acc[4][4] = {};
  for (int k0 = 0; k0 < K; k0 += 64) {
    __syncthreads();
#pragma unroll
    for (int i = 0; i < 4; ++i) {
      int rbase = wave * 32 + i * 8;
      int r = rbase + lrow;
      gload_lds16(A + (size_t)(m0 + r) * lda + k0 + lcol, &As[rbase * 64]);
      gload_lds16(B + (size_t)(n0 + r) * ldb + k0 + lcol, &Bs[rbase * 64]);
    }
    __syncthreads();
#pragma unroll
    for (int ks = 0; ks < 2; ++ks) {
      bf16x8 af[4], bb[4];
#pragma unroll
      for (int m = 0; m < 4; ++m)
        af[m] = *(const bf16x8*)&As[(wr + m * 16 + fr) * 64 + ks * 32 + fq * 8];
#pragma unroll
      for (int n = 0; n < 4; ++n)
        bb[n] = *(const bf16x8*)&Bs[(wc + n * 16 + fr) * 64 + ks * 32 + fq * 8];
#pragma unroll
      for (int m = 0; m < 4; ++m)
#pragma unroll
        for (int n = 0; n < 4; ++n)
          acc[m][n] = mfma16(af[m], bb[n], acc[m][n]);
    }
  }
#pragma unroll
  for (int m = 0; m < 4; ++m)
#pragma unroll
    for (int n = 0; n < 4; ++n)
#pragma unroll
      for (int i = 0; i < 4; ++i) {
        int r = m0 + wr + m * 16 + fq * 4 + i;
        int c = n0 + wc + n * 16 + fr;
        float vv = acc[m][n][i] * scale;
        if (OUT_F32) {
          float rs = ADD_RES ? res[(size_t)r * ldc + c] : 0.0f;
          __builtin_nontemporal_store(vv + rs, (float*)Cv + (size_t)r * ldc + c);
        } else {
          ((unsigned short*)Cv)[(size_t)r * ldc + c] = f2bf(vv);
        }
      }
}

// --------- V-projection GEMM with transposed scatter epilogue -------------
// C[token][dglob] -> Vt[((b*16+h)*64 + d) * 1024 + kk]
__global__ __launch_bounds__(256) void gemm_vt_k(const unsigned short* __restrict__ A, int lda,
                                                 const unsigned short* __restrict__ B, int ldb,
                                                 unsigned short* __restrict__ Vt, int K) {
  __shared__ __align__(16) unsigned short As[128 * 64];
  __shared__ __align__(16) unsigned short Bs[128 * 64];
  const int t = threadIdx.x;
  const int lane = t & 63, wave = t >> 6;
  const int fr = lane & 15, fq = lane >> 4;
  const int wr = (wave >> 1) * 64, wc = (wave & 1) * 64;
  const int m0 = blockIdx.y * 128, n0 = blockIdx.x * 128;
  const int lrow = lane >> 3, lcol = (lane & 7) * 8;
  f32x4 acc[4][4] = {};
  for (int k0 = 0; k0 < K; k0 += 64) {
    __syncthreads();
#pragma unroll
    for (int i = 0; i < 4; ++i) {
      int rbase = wave * 32 + i * 8;
      int r = rbase + lrow;
      gload_lds16(A + (size_t)(m0 + r) * lda + k0 + lcol, &As[rbase * 64]);
      gload_lds16(B + (size_t)(n0 + r) * ldb + k0 + lcol, &Bs[rbase * 64]);
    }
    __syncthreads();
#pragma unroll
    for (int ks = 0; ks < 2; ++ks) {
      bf16x8 af[4], bb[4];
#pragma unroll
      for (int m = 0; m < 4; ++m)
        af[m] = *(const bf16x8*)&As[(wr + m * 16 + fr) * 64 + ks * 32 + fq * 8];
#pragma unroll
      for (int n = 0; n < 4; ++n)
        bb[n] = *(const bf16x8*)&Bs[(wc + n * 16 + fr) * 64 + ks * 32 + fq * 8];
#pragma unroll
      for (int m = 0; m < 4; ++m)
#pragma unroll
        for (int n = 0; n < 4; ++n)
          acc[m][n] = mfma16(af[m], bb[n], acc[m][n]);
    }
  }
#pragma unroll
  for (int m = 0; m < 4; ++m)
#pragma unroll
    for (int n = 0; n < 4; ++n)
#pragma unroll
      for (int i = 0; i < 4; ++i) {
        int r = m0 + wr + m * 16 + fq * 4 + i;   // token row = kk*8 + b
        int c = n0 + wc + n * 16 + fr;           // dglob = h*64 + d
        int kk = r >> 3, b_ = r & 7, h_ = c >> 6, d_ = c & 63;
        Vt[(((size_t)(b_ * 16 + h_) * 64 + d_) << 10) + kk] = f2bf(acc[m][n][i]);
      }
}

// ---------------- fused scores+softmax+PV (two-pass flash) ----------------
// grid: 2048 blocks (1D), 256 threads / 4 waves, QBLK=64 (r12 structure).
// K staging via global_load_lds (async, no VGPR round-trip; linear [128][64]
// LDS, 16-way read conflicts accepted at this 2-barrier regime). V staging
// and all barriers unchanged from r12. XCD-aware remap; no max-tracking;
// attn stores non-temporal; Ps 64x128 XOR-swizzled.
__global__ __launch_bounds__(256, 2) void attn_fused_k(
    const unsigned short* __restrict__ Q,   // [token][1024], pre-scaled by 0.125*log2e
    const unsigned short* __restrict__ K,   // [token][1024]
    const unsigned short* __restrict__ Vt,  // [(b*16+h)*64 + d][1024 kk]
    const unsigned char* __restrict__ mask,
    float* __restrict__ attn,               // [bh][1024 q][1024 k]
    unsigned short* __restrict__ ctx) {     // [token][1024]
  __shared__ __align__(16) unsigned short KVu[128 * 72];  // K [128][64] linear OR V^T [64][136]
  __shared__ __align__(16) unsigned short Ps[64 * 128];   // P bf16, XOR-swizzled rows
  __shared__ float lrow[64];
  __shared__ float ps2[64][2], maskv[128];

  const int t = threadIdx.x;
  const int lane = t & 63, wave = t >> 6;
  const int fr = lane & 15, fq = lane >> 4;
  // XCD-aware (qt, bh) assignment from linear dispatch id
  const int L = blockIdx.x;                 // 0..2047, dispatch order
  const int xcd = L & 7;
  const int idx = L >> 3;                   // 0..255
  const int bh = xcd * 16 + (idx >> 4);
  const int qt = idx & 15;                  // 16 q-tiles of 64 rows
  const int b = bh >> 4, h = bh & 15;
  const int wrk = (wave >> 1) * 64;   // k-dim strip (S^T rows)
  const int wcq = (wave & 1) * 32;    // q-dim strip (S^T cols), 32 wide
  const int w01 = wave >> 1;
  const int swz = (fr & 7) << 4;      // per-lane Ps byte swizzle (row%8 == fr%8)
  const int lrow2 = lane >> 3, lcol2 = (lane & 7) * 8;  // K stage lane coords

  // Q fragments: loop-invariant, registers (64 q rows)
  bf16x8 qf[2][2];
#pragma unroll
  for (int n = 0; n < 2; ++n)
#pragma unroll
    for (int c = 0; c < 2; ++c)
      qf[n][c] = *(const bf16x8*)(Q +
          (((size_t)(qt * 64 + wcq + n * 16 + fr) * 8 + b) << 10) + h * 64 + c * 32 + fq * 8);

  // ================= pass 1: denominator only (register-resident) =========
  float s_run[2] = {0.0f, 0.0f};
  for (int kt = 0; kt < 8; ++kt) {
    __syncthreads();
    // async K stage: 4 issues/wave, 8 rows each, linear dest
#pragma unroll
    for (int i = 0; i < 4; ++i) {
      int rbase = wave * 32 + i * 8;
      gload_lds16(K + (((size_t)(kt * 128 + rbase + lrow2) * 8 + b) << 10) + h * 64 + lcol2,
                  &KVu[rbase * 64]);
    }
    if (t < 128) maskv[t] = mask[b * 1024 + kt * 128 + t] ? -1.0e9f : 0.0f;
    __syncthreads();   // drains vmcnt -> gload_lds complete
    f32x4 acc[4][2] = {};
#pragma unroll
    for (int k0 = 0; k0 < 2; ++k0) {
      bf16x8 af[4];
#pragma unroll
      for (int m = 0; m < 4; ++m)
        af[m] = *(const bf16x8*)&KVu[(wrk + m * 16 + fr) * 64 + k0 * 32 + fq * 8];
      __builtin_amdgcn_s_setprio(1);
#pragma unroll
      for (int m = 0; m < 4; ++m)
#pragma unroll
        for (int n = 0; n < 2; ++n)
          acc[m][n] = mfma16(af[m], qf[n][k0], acc[m][n]);
      __builtin_amdgcn_s_setprio(0);
    }
    float4 mk[4];
#pragma unroll
    for (int m = 0; m < 4; ++m) mk[m] = *(const float4*)&maskv[wrk + m * 16 + fq * 4];
#pragma unroll
    for (int n = 0; n < 2; ++n) {
      float s = 0.0f;
#pragma unroll
      for (int m = 0; m < 4; ++m) {
        s += __builtin_amdgcn_exp2f(acc[m][n][0] + mk[m].x);
        s += __builtin_amdgcn_exp2f(acc[m][n][1] + mk[m].y);
        s += __builtin_amdgcn_exp2f(acc[m][n][2] + mk[m].z);
        s += __builtin_amdgcn_exp2f(acc[m][n][3] + mk[m].w);
      }
      s_run[n] += s;
    }
  }
  // final cross-lane + cross-wave denominator merge (once)
#pragma unroll
  for (int n = 0; n < 2; ++n) {
    float s = s_run[n];
    s += __shfl_xor(s, 16);
    s += __shfl_xor(s, 32);
    if (fq == 0) ps2[wcq + n * 16 + fr][w01] = s;
  }
  __syncthreads();
  if (t < 64) lrow[t] = 1.0f / (ps2[t][0] + ps2[t][1]);

  // ================= pass 2: P write + attn store + PV =================
  const int wq = (wave >> 1) * 32, wd = (wave & 1) * 32;
  f32x4 accv[2][2] = {};
  for (int kt = 0; kt < 8; ++kt) {
    __syncthreads();
#pragma unroll
    for (int i = 0; i < 4; ++i) {
      int rbase = wave * 32 + i * 8;
      gload_lds16(K + (((size_t)(kt * 128 + rbase + lrow2) * 8 + b) << 10) + h * 64 + lcol2,
                  &KVu[rbase * 64]);
    }
    if (t < 128) maskv[t] = mask[b * 1024 + kt * 128 + t] ? -1.0e9f : 0.0f;
    __syncthreads();   // drains vmcnt -> gload_lds complete
    f32x4 acc[4][2] = {};
#pragma unroll
    for (int k0 = 0; k0 < 2; ++k0) {
      bf16x8 af[4];
#pragma unroll
      for (int m = 0; m < 4; ++m)
        af[m] = *(const bf16x8*)&KVu[(wrk + m * 16 + fr) * 64 + k0 * 32 + fq * 8];
      __builtin_amdgcn_s_setprio(1);
#pragma unroll
      for (int m = 0; m < 4; ++m)
#pragma unroll
        for (int n = 0; n < 2; ++n)
          acc[m][n] = mfma16(af[m], qf[n][k0], acc[m][n]);
      __builtin_amdgcn_s_setprio(0);
    }
    float4 mk[4];
#pragma unroll
    for (int m = 0; m < 4; ++m) mk[m] = *(const float4*)&maskv[wrk + m * 16 + fq * 4];
#pragma unroll
    for (int m = 0; m < 4; ++m)
#pragma unroll
      for (int n = 0; n < 2; ++n) {
        acc[m][n][0] += mk[m].x; acc[m][n][1] += mk[m].y;
        acc[m][n][2] += mk[m].z; acc[m][n][3] += mk[m].w;
      }
    float il[2];
#pragma unroll
    for (int n = 0; n < 2; ++n) il[n] = lrow[wcq + n * 16 + fr];
#pragma unroll
    for (int m = 0; m < 4; ++m) {
      int k4 = wrk + m * 16 + fq * 4;
#pragma unroll
      for (int n = 0; n < 2; ++n) {
        float p0 = __builtin_amdgcn_exp2f(acc[m][n][0]) * il[n];
        float p1 = __builtin_amdgcn_exp2f(acc[m][n][1]) * il[n];
        float p2 = __builtin_amdgcn_exp2f(acc[m][n][2]) * il[n];
        float p3 = __builtin_amdgcn_exp2f(acc[m][n][3]) * il[n];
        uint2 w;
        w.x = f2bf(p0) | ((unsigned)f2bf(p1) << 16);
        w.y = f2bf(p2) | ((unsigned)f2bf(p3) << 16);
        int row = wcq + n * 16 + fr;
        *(uint2*)((char*)Ps + row * 256 + ((k4 * 2) ^ swz)) = w;
      }
    }
    __syncthreads();
    // coalesced attn write (from Ps, non-temporal f32x4) + V^T tile load
#pragma unroll
    for (int it = 0; it < 8; ++it) {
      int idx2 = it * 256 + t;
      int row = idx2 >> 5, colb = (idx2 & 31) << 3;   // 8 bytes per lane
      uint2 d2 = *(const uint2*)((const char*)Ps + row * 256 + (colb ^ ((row & 7) << 4)));
      f32x4 o;
      o[0] = bf2f((unsigned short)(d2.x & 0xFFFF));
      o[1] = bf2f((unsigned short)(d2.x >> 16));
      o[2] = bf2f((unsigned short)(d2.y & 0xFFFF));
      o[3] = bf2f((unsigned short)(d2.y >> 16));
      __builtin_nontemporal_store(
          o, (f32x4*)(attn + ((size_t)bh * 1024 + qt * 64 + row) * 1024 + kt * 128 + (colb >> 1)));
    }
#pragma unroll
    for (int it = 0; it < 4; ++it) {
      int dd = (it * 256 + t) >> 4, k8 = ((it * 256 + t) & 15) << 3;
      *(uint4*)&KVu[dd * 136 + k8] =
          *(const uint4*)(Vt + (((size_t)(b * 16 + h) * 64 + dd) << 10) + kt * 128 + k8);
    }
    __syncthreads();
    // PV: ctx[q][d] += P[q][k] * V[k][d]
#pragma unroll
    for (int ks = 0; ks < 4; ++ks) {
      bf16x8 pa[2], vb[2];
#pragma unroll
      for (int m2 = 0; m2 < 2; ++m2) {
        int row = wq + m2 * 16 + fr;
        pa[m2] = *(const bf16x8*)((const char*)Ps + row * 256 + (((ks * 32 + fq * 8) * 2) ^ swz));
      }
#pragma unroll
      for (int n2 = 0; n2 < 2; ++n2)
        vb[n2] = *(const bf16x8*)&KVu[(wd + n2 * 16 + fr) * 136 + ks * 32 + fq * 8];
      __builtin_amdgcn_s_setprio(1);
#pragma unroll
      for (int m2 = 0; m2 < 2; ++m2)
#pragma unroll
        for (int n2 = 0; n2 < 2; ++n2)
          accv[m2][n2] = mfma16(pa[m2], vb[n2], accv[m2][n2]);
      __builtin_amdgcn_s_setprio(0);
    }
  }
  // ctx epilogue
#pragma unroll
  for (int m2 = 0; m2 < 2; ++m2)
#pragma unroll
    for (int n2 = 0; n2 < 2; ++n2)
#pragma unroll
      for (int i = 0; i < 4; ++i) {
        int qrow = qt * 64 + wq + m2 * 16 + fq * 4 + i;
        int c = h * 64 + wd + n2 * 16 + fr;
        ctx[(((size_t)qrow * 8 + b) << 10) + c] = f2bf(accv[m2][n2][i]);
      }
}

extern "C" void kernel_launch(void* const* d_in, const int* in_sizes, int n_in,
                              void* d_out, int out_size, void* d_ws, size_t ws_size,
                              hipStream_t stream) {
  const float* q = (const float*)d_in[0];
  const float* k = (const float*)d_in[1];
  const unsigned char* mask = (const unsigned char*)d_in[2];
  const float* Wq = (const float*)d_in[3];
  const float* Wkv = (const float*)d_in[4];
  const float* Wo = (const float*)d_in[5];
  const float* ln_g = (const float*)d_in[6];
  const float* ln_b = (const float*)d_in[7];

  float* out0 = (float*)d_out;                   // (1024,8,1024)
  float* attn = out0 + (size_t)LQ * BB * DD;     // (8,16,1024,1024)

  char* ws = (char*)d_ws;
  unsigned short* qn   = (unsigned short*)(ws);                        // 16 MB
  unsigned short* kbf  = (unsigned short*)(ws + ((size_t)16 << 20));   // 16 MB
  unsigned short* Qw   = (unsigned short*)(ws + ((size_t)32 << 20));   // 16 MB
  unsigned short* ctxw = (unsigned short*)(ws + ((size_t)48 << 20));   // 16 MB
  unsigned short* Kw   = (unsigned short*)(ws + ((size_t)64 << 20));   // 16 MB
  unsigned short* Vtg  = (unsigned short*)(ws + ((size_t)80 << 20));   // 16 MB
  unsigned short* Wqb  = (unsigned short*)(ws + ((size_t)96 << 20));   // 2 MB
  unsigned short* Wkvb = (unsigned short*)(ws + ((size_t)98 << 20));   // 4 MB
  unsigned short* Wob  = (unsigned short*)(ws + ((size_t)102 << 20));  // 2 MB

  cvt_k<<<8192, 256, 0, stream>>>(k, kbf, (LK * BB * DD) / 4);
  cvtW_k<<<4096, 256, 0, stream>>>(Wq, Wkv, Wo, Wqb, Wkvb, Wob);

  layernorm_k<<<LQ * BB, 256, 0, stream>>>(q, ln_g, ln_b, qn);

  // Q = qn @ Wq^T * (0.125 * log2e)  -> scores in log2 domain
  gemm_bt_k<false, false><<<dim3(8, 64), 256, 0, stream>>>(
      qn, DD, Wqb, DD, Qw, DD, nullptr, 0.18033688011112f, DD);

  // K = k @ Wk^T (first half of Wkv)
  gemm_bt_k<false, false><<<dim3(8, 64), 256, 0, stream>>>(
      kbf, DD, Wkvb, DD, Kw, DD, nullptr, 1.0f, DD);

  // V^T = transpose-scatter of k @ Wv^T (second half of Wkv)
  gemm_vt_k<<<dim3(8, 64), 256, 0, stream>>>(
      kbf, DD, Wkvb + ((size_t)1 << 20), DD, Vtg, DD);

  // fused scores+softmax+PV  (1D grid, 2048 blocks, XCD-aware remap)
  attn_fused_k<<<dim3(16 * BB * HH), 256, 0, stream>>>(Qw, Kw, Vtg, mask, attn, ctxw);

  // out = ctx @ Wo^T + residual
  gemm_bt_k<true, true><<<dim3(8, 64), 256, 0, stream>>>(
      ctxw, DD, Wob, DD, out0, DD, q, 1.0f, DD);
}

// Round 20
// 284.713 us; speedup vs baseline: 1.1371x; 1.0125x over previous
//
#include <hip/hip_runtime.h>
#include <stdint.h>

typedef __bf16 bf16x8 __attribute__((ext_vector_type(8)));
typedef float f32x4 __attribute__((ext_vector_type(4)));

#define LQ 1024
#define LK 1024
#define BB 8
#define DD 1024
#define HH 16
#define DK 64

__device__ __forceinline__ unsigned short f2bf(float f) {
  union { float f; unsigned u; } v; v.f = f;
  unsigned u = v.u;
  u += 0x7FFFu + ((u >> 16) & 1u);   // RNE
  return (unsigned short)(u >> 16);
}
__device__ __forceinline__ float bf2f(unsigned short u) {
  union { unsigned u; float f; } v; v.u = ((unsigned)u) << 16;
  return v.f;
}
__device__ __forceinline__ f32x4 mfma16(bf16x8 a, bf16x8 b, f32x4 c) {
  return __builtin_amdgcn_mfma_f32_16x16x32_bf16(a, b, c, 0, 0, 0);
}
// async global->LDS, 16B per lane; LDS dest is wave-uniform base + lane*16
__device__ __forceinline__ void gload_lds16(const unsigned short* g, unsigned short* l) {
  __builtin_amdgcn_global_load_lds(
      (const __attribute__((address_space(1))) void*)g,
      (__attribute__((address_space(3))) void*)l, 16, 0, 0);
}

// ------ fused prologue: k->bf16 | weight cvts | layernorm, ONE launch -----
// blocks [0,8192): cvt k (2M float4)
// blocks [8192,12288): cvt Wq|Wkv|Wo (1M float4)
// blocks [12288,20480): layernorm rows (8192 rows)
__global__ __launch_bounds__(256) void prologue_k(
    const float* __restrict__ kin, unsigned short* __restrict__ kbf,
    const float* __restrict__ Wq, const float* __restrict__ Wkv,
    const float* __restrict__ Wo, unsigned short* __restrict__ oq,
    unsigned short* __restrict__ okv, unsigned short* __restrict__ oo,
    const float* __restrict__ x, const float* __restrict__ g,
    const float* __restrict__ bta, unsigned short* __restrict__ xout) {
  const int blk = blockIdx.x;
  const int t = threadIdx.x;
  if (blk < 8192) {
    // ---- cvt k ----
    int i = blk * 256 + t;
    float4 v = *(const float4*)(kin + (size_t)i * 4);
    uint2 o;
    o.x = f2bf(v.x) | ((unsigned)f2bf(v.y) << 16);
    o.y = f2bf(v.z) | ((unsigned)f2bf(v.w) << 16);
    *(uint2*)(kbf + (size_t)i * 4) = o;
  } else if (blk < 12288) {
    // ---- cvt weights ----
    int i = (blk - 8192) * 256 + t;   // 0..1M float4
    const float* in;
    unsigned short* out;
    int j;
    if (i < 262144) { in = Wq; out = oq; j = i; }
    else if (i < 786432) { in = Wkv; out = okv; j = i - 262144; }
    else { in = Wo; out = oo; j = i - 786432; }
    float4 v = *(const float4*)(in + (size_t)j * 4);
    uint2 o;
    o.x = f2bf(v.x) | ((unsigned)f2bf(v.y) << 16);
    o.y = f2bf(v.z) | ((unsigned)f2bf(v.w) << 16);
    *(uint2*)(out + (size_t)j * 4) = o;
  } else {
    // ---- layernorm ----
    const int row = blk - 12288;
    const float* xr = x + (size_t)row * DD;
    float4 v = *(const float4*)(xr + t * 4);
    float s = v.x + v.y + v.z + v.w;
    float s2 = v.x * v.x + v.y * v.y + v.z * v.z + v.w * v.w;
    for (int off = 32; off > 0; off >>= 1) {
      s += __shfl_down(s, off);
      s2 += __shfl_down(s2, off);
    }
    __shared__ float red[8];
    int lane = t & 63, w = t >> 6;
    if (lane == 0) { red[w] = s; red[4 + w] = s2; }
    __syncthreads();
    s = red[0] + red[1] + red[2] + red[3];
    s2 = red[4] + red[5] + red[6] + red[7];
    float mu = s * (1.0f / 1024.0f);
    float var = s2 * (1.0f / 1024.0f) - mu * mu;
    float inv = rsqrtf(var + 1e-5f);
    float4 gv = *(const float4*)(g + t * 4);
    float4 bv = *(const float4*)(bta + t * 4);
    uint2 o;
    o.x = f2bf((v.x - mu) * inv * gv.x + bv.x) |
          ((unsigned)f2bf((v.y - mu) * inv * gv.y + bv.y) << 16);
    o.y = f2bf((v.z - mu) * inv * gv.z + bv.z) |
          ((unsigned)f2bf((v.w - mu) * inv * gv.w + bv.w) << 16);
    *(uint2*)(xout + (size_t)row * DD + t * 4) = o;
  }
}

// ---------------- generic C = scale * A @ B^T  (+residual) ----------------
// m97 structure: BK=64, global_load_lds width-16 staging, linear LDS tiles.
template <bool OUT_F32, bool ADD_RES>
__global__ __launch_bounds__(256) void gemm_bt_k(const unsigned short* __restrict__ A, int lda,
                                                 const unsigned short* __restrict__ B, int ldb,
                                                 void* __restrict__ Cv, int ldc,
                                                 const float* __restrict__ res,
                                                 float scale, int K) {
  __shared__ __align__(16) unsigned short As[128 * 64];
  __shared__ __align__(16) unsigned short Bs[128 * 64];
  const int t = threadIdx.x;
  const int lane = t & 63, wave = t >> 6;
  const int fr = lane & 15, fq = lane >> 4;
  const int wr = (wave >> 1) * 64, wc = (wave & 1) * 64;
  const int m0 = blockIdx.y * 128, n0 = blockIdx.x * 128;
  const int lrow = lane >> 3, lcol = (lane & 7) * 8;  // 8 rows x 64 cols per issue
  f32x4 acc[4][4] = {};
  for (int k0 = 0; k0 < K; k0 += 64) {
    __syncthreads();
#pragma unroll
    for (int i = 0; i < 4; ++i) {
      int rbase = wave * 32 + i * 8;
      int r = rbase + lrow;
      gload_lds16(A + (size_t)(m0 + r) * lda + k0 + lcol, &As[rbase * 64]);
      gload_lds16(B + (size_t)(n0 + r) * ldb + k0 + lcol, &Bs[rbase * 64]);
    }
    __syncthreads();
#pragma unroll
    for (int ks = 0; ks < 2; ++ks) {
      bf16x8 af[4], bb[4];
#pragma unroll
      for (int m = 0; m < 4; ++m)
        af[m] = *(const bf16x8*)&As[(wr + m * 16 + fr) * 64 + ks * 32 + fq * 8];
#pragma unroll
      for (int n = 0; n < 4; ++n)
        bb[n] = *(const bf16x8*)&Bs[(wc + n * 16 + fr) * 64 + ks * 32 + fq * 8];
#pragma unroll
      for (int m = 0; m < 4; ++m)
#pragma unroll
        for (int n = 0; n < 4; ++n)
          acc[m][n] = mfma16(af[m], bb[n], acc[m][n]);
    }
  }
#pragma unroll
  for (int m = 0; m < 4; ++m)
#pragma unroll
    for (int n = 0; n < 4; ++n)
#pragma unroll
      for (int i = 0; i < 4; ++i) {
        int r = m0 + wr + m * 16 + fq * 4 + i;
        int c = n0 + wc + n * 16 + fr;
        float vv = acc[m][n][i] * scale;
        if (OUT_F32) {
          float rs = ADD_RES ? res[(size_t)r * ldc + c] : 0.0f;
          __builtin_nontemporal_store(vv + rs, (float*)Cv + (size_t)r * ldc + c);
        } else {
          ((unsigned short*)Cv)[(size_t)r * ldc + c] = f2bf(vv);
        }
      }
}

// --------- V-projection GEMM with transposed scatter epilogue -------------
// C[token][dglob] -> Vt[((b*16+h)*64 + d) * 1024 + kk]
__global__ __launch_bounds__(256) void gemm_vt_k(const unsigned short* __restrict__ A, int lda,
                                                 const unsigned short* __restrict__ B, int ldb,
                                                 unsigned short* __restrict__ Vt, int K) {
  __shared__ __align__(16) unsigned short As[128 * 64];
  __shared__ __align__(16) unsigned short Bs[128 * 64];
  const int t = threadIdx.x;
  const int lane = t & 63, wave = t >> 6;
  const int fr = lane & 15, fq = lane >> 4;
  const int wr = (wave >> 1) * 64, wc = (wave & 1) * 64;
  const int m0 = blockIdx.y * 128, n0 = blockIdx.x * 128;
  const int lrow = lane >> 3, lcol = (lane & 7) * 8;
  f32x4 acc[4][4] = {};
  for (int k0 = 0; k0 < K; k0 += 64) {
    __syncthreads();
#pragma unroll
    for (int i = 0; i < 4; ++i) {
      int rbase = wave * 32 + i * 8;
      int r = rbase + lrow;
      gload_lds16(A + (size_t)(m0 + r) * lda + k0 + lcol, &As[rbase * 64]);
      gload_lds16(B + (size_t)(n0 + r) * ldb + k0 + lcol, &Bs[rbase * 64]);
    }
    __syncthreads();
#pragma unroll
    for (int ks = 0; ks < 2; ++ks) {
      bf16x8 af[4], bb[4];
#pragma unroll
      for (int m = 0; m < 4; ++m)
        af[m] = *(const bf16x8*)&As[(wr + m * 16 + fr) * 64 + ks * 32 + fq * 8];
#pragma unroll
      for (int n = 0; n < 4; ++n)
        bb[n] = *(const bf16x8*)&Bs[(wc + n * 16 + fr) * 64 + ks * 32 + fq * 8];
#pragma unroll
      for (int m = 0; m < 4; ++m)
#pragma unroll
        for (int n = 0; n < 4; ++n)
          acc[m][n] = mfma16(af[m], bb[n], acc[m][n]);
    }
  }
#pragma unroll
  for (int m = 0; m < 4; ++m)
#pragma unroll
    for (int n = 0; n < 4; ++n)
#pragma unroll
      for (int i = 0; i < 4; ++i) {
        int r = m0 + wr + m * 16 + fq * 4 + i;   // token row = kk*8 + b
        int c = n0 + wc + n * 16 + fr;           // dglob = h*64 + d
        int kk = r >> 3, b_ = r & 7, h_ = c >> 6, d_ = c & 63;
        Vt[(((size_t)(b_ * 16 + h_) * 64 + d_) << 10) + kk] = f2bf(acc[m][n][i]);
      }
}

// ---------------- fused scores+softmax+PV (two-pass flash) ----------------
// grid: 2048 blocks (1D), 256 threads / 4 waves, QBLK=64 (r16 structure).
// K staging via global_load_lds (async, no VGPR round-trip; linear [128][64]
// LDS, 16-way read conflicts accepted at this 2-barrier regime).
// XCD-aware remap; no max-tracking (log2-domain scores); attn stores
// non-temporal; Ps 64x128 XOR-swizzled.
__global__ __launch_bounds__(256, 2) void attn_fused_k(
    const unsigned short* __restrict__ Q,   // [token][1024], pre-scaled by 0.125*log2e
    const unsigned short* __restrict__ K,   // [token][1024]
    const unsigned short* __restrict__ Vt,  // [(b*16+h)*64 + d][1024 kk]
    const unsigned char* __restrict__ mask,
    float* __restrict__ attn,               // [bh][1024 q][1024 k]
    unsigned short* __restrict__ ctx) {     // [token][1024]
  __shared__ __align__(16) unsigned short KVu[128 * 72];  // K [128][64] linear OR V^T [64][136]
  __shared__ __align__(16) unsigned short Ps[64 * 128];   // P bf16, XOR-swizzled rows
  __shared__ float lrow[64];
  __shared__ float ps2[64][2], maskv[128];

  const int t = threadIdx.x;
  const int lane = t & 63, wave = t >> 6;
  const int fr = lane & 15, fq = lane >> 4;
  // XCD-aware (qt, bh) assignment from linear dispatch id
  const int L = blockIdx.x;                 // 0..2047, dispatch order
  const int xcd = L & 7;
  const int idx = L >> 3;                   // 0..255
  const int bh = xcd * 16 + (idx >> 4);
  const int qt = idx & 15;                  // 16 q-tiles of 64 rows
  const int b = bh >> 4, h = bh & 15;
  const int wrk = (wave >> 1) * 64;   // k-dim strip (S^T rows)
  const int wcq = (wave & 1) * 32;    // q-dim strip (S^T cols), 32 wide
  const int w01 = wave >> 1;
  const int swz = (fr & 7) << 4;      // per-lane Ps byte swizzle (row%8 == fr%8)
  const int lrow2 = lane >> 3, lcol2 = (lane & 7) * 8;  // K stage lane coords

  // Q fragments: loop-invariant, registers (64 q rows)
  bf16x8 qf[2][2];
#pragma unroll
  for (int n = 0; n < 2; ++n)
#pragma unroll
    for (int c = 0; c < 2; ++c)
      qf[n][c] = *(const bf16x8*)(Q +
          (((size_t)(qt * 64 + wcq + n * 16 + fr) * 8 + b) << 10) + h * 64 + c * 32 + fq * 8);

  // ================= pass 1: denominator only (register-resident) =========
  float s_run[2] = {0.0f, 0.0f};
  for (int kt = 0; kt < 8; ++kt) {
    __syncthreads();
    // async K stage: 4 issues/wave, 8 rows each, linear dest
#pragma unroll
    for (int i = 0; i < 4; ++i) {
      int rbase = wave * 32 + i * 8;
      gload_lds16(K + (((size_t)(kt * 128 + rbase + lrow2) * 8 + b) << 10) + h * 64 + lcol2,
                  &KVu[rbase * 64]);
    }
    if (t < 128) maskv[t] = mask[b * 1024 + kt * 128 + t] ? -1.0e9f : 0.0f;
    __syncthreads();   // drains vmcnt -> gload_lds complete
    f32x4 acc[4][2] = {};
#pragma unroll
    for (int k0 = 0; k0 < 2; ++k0) {
      bf16x8 af[4];
#pragma unroll
      for (int m = 0; m < 4; ++m)
        af[m] = *(const bf16x8*)&KVu[(wrk + m * 16 + fr) * 64 + k0 * 32 + fq * 8];
      __builtin_amdgcn_s_setprio(1);
#pragma unroll
      for (int m = 0; m < 4; ++m)
#pragma unroll
        for (int n = 0; n < 2; ++n)
          acc[m][n] = mfma16(af[m], qf[n][k0], acc[m][n]);
      __builtin_amdgcn_s_setprio(0);
    }
    float4 mk[4];
#pragma unroll
    for (int m = 0; m < 4; ++m) mk[m] = *(const float4*)&maskv[wrk + m * 16 + fq * 4];
#pragma unroll
    for (int n = 0; n < 2; ++n) {
      float s = 0.0f;
#pragma unroll
      for (int m = 0; m < 4; ++m) {
        s += __builtin_amdgcn_exp2f(acc[m][n][0] + mk[m].x);
        s += __builtin_amdgcn_exp2f(acc[m][n][1] + mk[m].y);
        s += __builtin_amdgcn_exp2f(acc[m][n][2] + mk[m].z);
        s += __builtin_amdgcn_exp2f(acc[m][n][3] + mk[m].w);
      }
      s_run[n] += s;
    }
  }
  // final cross-lane + cross-wave denominator merge (once)
#pragma unroll
  for (int n = 0; n < 2; ++n) {
    float s = s_run[n];
    s += __shfl_xor(s, 16);
    s += __shfl_xor(s, 32);
    if (fq == 0) ps2[wcq + n * 16 + fr][w01] = s;
  }
  __syncthreads();
  if (t < 64) lrow[t] = 1.0f / (ps2[t][0] + ps2[t][1]);

  // ================= pass 2: P write + attn store + PV =================
  const int wq = (wave >> 1) * 32, wd = (wave & 1) * 32;
  f32x4 accv[2][2] = {};
  for (int kt = 0; kt < 8; ++kt) {
    __syncthreads();
#pragma unroll
    for (int i = 0; i < 4; ++i) {
      int rbase = wave * 32 + i * 8;
      gload_lds16(K + (((size_t)(kt * 128 + rbase + lrow2) * 8 + b) << 10) + h * 64 + lcol2,
                  &KVu[rbase * 64]);
    }
    if (t < 128) maskv[t] = mask[b * 1024 + kt * 128 + t] ? -1.0e9f : 0.0f;
    __syncthreads();   // drains vmcnt -> gload_lds complete
    f32x4 acc[4][2] = {};
#pragma unroll
    for (int k0 = 0; k0 < 2; ++k0) {
      bf16x8 af[4];
#pragma unroll
      for (int m = 0; m < 4; ++m)
        af[m] = *(const bf16x8*)&KVu[(wrk + m * 16 + fr) * 64 + k0 * 32 + fq * 8];
      __builtin_amdgcn_s_setprio(1);
#pragma unroll
      for (int m = 0; m < 4; ++m)
#pragma unroll
        for (int n = 0; n < 2; ++n)
          acc[m][n] = mfma16(af[m], qf[n][k0], acc[m][n]);
      __builtin_amdgcn_s_setprio(0);
    }
    float4 mk[4];
#pragma unroll
    for (int m = 0; m < 4; ++m) mk[m] = *(const float4*)&maskv[wrk + m * 16 + fq * 4];
#pragma unroll
    for (int m = 0; m < 4; ++m)
#pragma unroll
      for (int n = 0; n < 2; ++n) {
        acc[m][n][0] += mk[m].x; acc[m][n][1] += mk[m].y;
        acc[m][n][2] += mk[m].z; acc[m][n][3] += mk[m].w;
      }
    float il[2];
#pragma unroll
    for (int n = 0; n < 2; ++n) il[n] = lrow[wcq + n * 16 + fr];
#pragma unroll
    for (int m = 0; m < 4; ++m) {
      int k4 = wrk + m * 16 + fq * 4;
#pragma unroll
      for (int n = 0; n < 2; ++n) {
        float p0 = __builtin_amdgcn_exp2f(acc[m][n][0]) * il[n];
        float p1 = __builtin_amdgcn_exp2f(acc[m][n][1]) * il[n];
        float p2 = __builtin_amdgcn_exp2f(acc[m][n][2]) * il[n];
        float p3 = __builtin_amdgcn_exp2f(acc[m][n][3]) * il[n];
        uint2 w;
        w.x = f2bf(p0) | ((unsigned)f2bf(p1) << 16);
        w.y = f2bf(p2) | ((unsigned)f2bf(p3) << 16);
        int row = wcq + n * 16 + fr;
        *(uint2*)((char*)Ps + row * 256 + ((k4 * 2) ^ swz)) = w;
      }
    }
    __syncthreads();
    // coalesced attn write (from Ps, non-temporal f32x4) + V^T tile load
#pragma unroll
    for (int it = 0; it < 8; ++it) {
      int idx2 = it * 256 + t;
      int row = idx2 >> 5, colb = (idx2 & 31) << 3;   // 8 bytes per lane
      uint2 d2 = *(const uint2*)((const char*)Ps + row * 256 + (colb ^ ((row & 7) << 4)));
      f32x4 o;
      o[0] = bf2f((unsigned short)(d2.x & 0xFFFF));
      o[1] = bf2f((unsigned short)(d2.x >> 16));
      o[2] = bf2f((unsigned short)(d2.y & 0xFFFF));
      o[3] = bf2f((unsigned short)(d2.y >> 16));
      __builtin_nontemporal_store(
          o, (f32x4*)(attn + ((size_t)bh * 1024 + qt * 64 + row) * 1024 + kt * 128 + (colb >> 1)));
    }
#pragma unroll
    for (int it = 0; it < 4; ++it) {
      int dd = (it * 256 + t) >> 4, k8 = ((it * 256 + t) & 15) << 3;
      *(uint4*)&KVu[dd * 136 + k8] =
          *(const uint4*)(Vt + (((size_t)(b * 16 + h) * 64 + dd) << 10) + kt * 128 + k8);
    }
    __syncthreads();
    // PV: ctx[q][d] += P[q][k] * V[k][d]
#pragma unroll
    for (int ks = 0; ks < 4; ++ks) {
      bf16x8 pa[2], vb[2];
#pragma unroll
      for (int m2 = 0; m2 < 2; ++m2) {
        int row = wq + m2 * 16 + fr;
        pa[m2] = *(const bf16x8*)((const char*)Ps + row * 256 + (((ks * 32 + fq * 8) * 2) ^ swz));
      }
#pragma unroll
      for (int n2 = 0; n2 < 2; ++n2)
        vb[n2] = *(const bf16x8*)&KVu[(wd + n2 * 16 + fr) * 136 + ks * 32 + fq * 8];
      __builtin_amdgcn_s_setprio(1);
#pragma unroll
      for (int m2 = 0; m2 < 2; ++m2)
#pragma unroll
        for (int n2 = 0; n2 < 2; ++n2)
          accv[m2][n2] = mfma16(pa[m2], vb[n2], accv[m2][n2]);
      __builtin_amdgcn_s_setprio(0);
    }
  }
  // ctx epilogue
#pragma unroll
  for (int m2 = 0; m2 < 2; ++m2)
#pragma unroll
    for (int n2 = 0; n2 < 2; ++n2)
#pragma unroll
      for (int i = 0; i < 4; ++i) {
        int qrow = qt * 64 + wq + m2 * 16 + fq * 4 + i;
        int c = h * 64 + wd + n2 * 16 + fr;
        ctx[(((size_t)qrow * 8 + b) << 10) + c] = f2bf(accv[m2][n2][i]);
      }
}

extern "C" void kernel_launch(void* const* d_in, const int* in_sizes, int n_in,
                              void* d_out, int out_size, void* d_ws, size_t ws_size,
                              hipStream_t stream) {
  const float* q = (const float*)d_in[0];
  const float* k = (const float*)d_in[1];
  const unsigned char* mask = (const unsigned char*)d_in[2];
  const float* Wq = (const float*)d_in[3];
  const float* Wkv = (const float*)d_in[4];
  const float* Wo = (const float*)d_in[5];
  const float* ln_g = (const float*)d_in[6];
  const float* ln_b = (const float*)d_in[7];

  float* out0 = (float*)d_out;                   // (1024,8,1024)
  float* attn = out0 + (size_t)LQ * BB * DD;     // (8,16,1024,1024)

  char* ws = (char*)d_ws;
  unsigned short* qn   = (unsigned short*)(ws);                        // 16 MB
  unsigned short* kbf  = (unsigned short*)(ws + ((size_t)16 << 20));   // 16 MB
  unsigned short* Qw   = (unsigned short*)(ws + ((size_t)32 << 20));   // 16 MB
  unsigned short* ctxw = (unsigned short*)(ws + ((size_t)48 << 20));   // 16 MB
  unsigned short* Kw   = (unsigned short*)(ws + ((size_t)64 << 20));   // 16 MB
  unsigned short* Vtg  = (unsigned short*)(ws + ((size_t)80 << 20));   // 16 MB
  unsigned short* Wqb  = (unsigned short*)(ws + ((size_t)96 << 20));   // 2 MB
  unsigned short* Wkvb = (unsigned short*)(ws + ((size_t)98 << 20));   // 4 MB
  unsigned short* Wob  = (unsigned short*)(ws + ((size_t)102 << 20));  // 2 MB

  // fused prologue: k cvt + weight cvts + layernorm in one launch
  prologue_k<<<20480, 256, 0, stream>>>(k, kbf, Wq, Wkv, Wo, Wqb, Wkvb, Wob,
                                        q, ln_g, ln_b, qn);

  // Q = qn @ Wq^T * (0.125 * log2e)  -> scores in log2 domain
  gemm_bt_k<false, false><<<dim3(8, 64), 256, 0, stream>>>(
      qn, DD, Wqb, DD, Qw, DD, nullptr, 0.18033688011112f, DD);

  // K = k @ Wk^T (first half of Wkv)
  gemm_bt_k<false, false><<<dim3(8, 64), 256, 0, stream>>>(
      kbf, DD, Wkvb, DD, Kw, DD, nullptr, 1.0f, DD);

  // V^T = transpose-scatter of k @ Wv^T (second half of Wkv)
  gemm_vt_k<<<dim3(8, 64), 256, 0, stream>>>(
      kbf, DD, Wkvb + ((size_t)1 << 20), DD, Vtg, DD);

  // fused scores+softmax+PV  (1D grid, 2048 blocks, XCD-aware remap)
  attn_fused_k<<<dim3(16 * BB * HH), 256, 0, stream>>>(Qw, Kw, Vtg, mask, attn, ctxw);

  // out = ctx @ Wo^T + residual
  gemm_bt_k<true, true><<<dim3(8, 64), 256, 0, stream>>>(
      ctxw, DD, Wob, DD, out0, DD, q, 1.0f, DD);
}

// Round 21
// 275.302 us; speedup vs baseline: 1.1759x; 1.0342x over previous
//
#include <hip/hip_runtime.h>
#include <stdint.h>

typedef __bf16 bf16x8 __attribute__((ext_vector_type(8)));
typedef float f32x4 __attribute__((ext_vector_type(4)));

#define LQ 1024
#define LK 1024
#define BB 8
#define DD 1024
#define HH 16
#define DK 64

__device__ __forceinline__ unsigned short f2bf(float f) {
  union { float f; unsigned u; } v; v.f = f;
  unsigned u = v.u;
  u += 0x7FFFu + ((u >> 16) & 1u);   // RNE
  return (unsigned short)(u >> 16);
}
__device__ __forceinline__ float bf2f(unsigned short u) {
  union { unsigned u; float f; } v; v.u = ((unsigned)u) << 16;
  return v.f;
}
__device__ __forceinline__ f32x4 mfma16(bf16x8 a, bf16x8 b, f32x4 c) {
  return __builtin_amdgcn_mfma_f32_16x16x32_bf16(a, b, c, 0, 0, 0);
}
// async global->LDS, 16B per lane; LDS dest is wave-uniform base + lane*16
__device__ __forceinline__ void gload_lds16(const unsigned short* g, unsigned short* l) {
  __builtin_amdgcn_global_load_lds(
      (const __attribute__((address_space(1))) void*)g,
      (__attribute__((address_space(3))) void*)l, 16, 0, 0);
}

// ------ fused prologue: k->bf16 | weight cvts | layernorm, ONE launch -----
// blocks [0,8192): cvt k (2M float4)
// blocks [8192,12288): cvt Wq|Wkv|Wo (1M float4)
// blocks [12288,20480): layernorm rows (8192 rows)
__global__ __launch_bounds__(256) void prologue_k(
    const float* __restrict__ kin, unsigned short* __restrict__ kbf,
    const float* __restrict__ Wq, const float* __restrict__ Wkv,
    const float* __restrict__ Wo, unsigned short* __restrict__ oq,
    unsigned short* __restrict__ okv, unsigned short* __restrict__ oo,
    const float* __restrict__ x, const float* __restrict__ g,
    const float* __restrict__ bta, unsigned short* __restrict__ xout) {
  const int blk = blockIdx.x;
  const int t = threadIdx.x;
  if (blk < 8192) {
    // ---- cvt k ----
    int i = blk * 256 + t;
    float4 v = *(const float4*)(kin + (size_t)i * 4);
    uint2 o;
    o.x = f2bf(v.x) | ((unsigned)f2bf(v.y) << 16);
    o.y = f2bf(v.z) | ((unsigned)f2bf(v.w) << 16);
    *(uint2*)(kbf + (size_t)i * 4) = o;
  } else if (blk < 12288) {
    // ---- cvt weights ----
    int i = (blk - 8192) * 256 + t;   // 0..1M float4
    const float* in;
    unsigned short* out;
    int j;
    if (i < 262144) { in = Wq; out = oq; j = i; }
    else if (i < 786432) { in = Wkv; out = okv; j = i - 262144; }
    else { in = Wo; out = oo; j = i - 786432; }
    float4 v = *(const float4*)(in + (size_t)j * 4);
    uint2 o;
    o.x = f2bf(v.x) | ((unsigned)f2bf(v.y) << 16);
    o.y = f2bf(v.z) | ((unsigned)f2bf(v.w) << 16);
    *(uint2*)(out + (size_t)j * 4) = o;
  } else {
    // ---- layernorm ----
    const int row = blk - 12288;
    const float* xr = x + (size_t)row * DD;
    float4 v = *(const float4*)(xr + t * 4);
    float s = v.x + v.y + v.z + v.w;
    float s2 = v.x * v.x + v.y * v.y + v.z * v.z + v.w * v.w;
    for (int off = 32; off > 0; off >>= 1) {
      s += __shfl_down(s, off);
      s2 += __shfl_down(s2, off);
    }
    __shared__ float red[8];
    int lane = t & 63, w = t >> 6;
    if (lane == 0) { red[w] = s; red[4 + w] = s2; }
    __syncthreads();
    s = red[0] + red[1] + red[2] + red[3];
    s2 = red[4] + red[5] + red[6] + red[7];
    float mu = s * (1.0f / 1024.0f);
    float var = s2 * (1.0f / 1024.0f) - mu * mu;
    float inv = rsqrtf(var + 1e-5f);
    float4 gv = *(const float4*)(g + t * 4);
    float4 bv = *(const float4*)(bta + t * 4);
    uint2 o;
    o.x = f2bf((v.x - mu) * inv * gv.x + bv.x) |
          ((unsigned)f2bf((v.y - mu) * inv * gv.y + bv.y) << 16);
    o.y = f2bf((v.z - mu) * inv * gv.z + bv.z) |
          ((unsigned)f2bf((v.w - mu) * inv * gv.w + bv.w) << 16);
    *(uint2*)(xout + (size_t)row * DD + t * 4) = o;
  }
}

// ------- fused projection GEMMs: Q | K | V^T in ONE 1536-block launch -----
// blocks [0,512):    Qw  = qn  @ Wq^T * (0.125*log2e)   (bf16 out)
// blocks [512,1024): Kw  = kbf @ Wk^T                   (bf16 out)
// blocks [1024,1536): Vt = transpose-scatter(kbf @ Wv^T)
// m97 structure: BK=64, global_load_lds width-16 staging, linear LDS tiles.
__global__ __launch_bounds__(256) void proj_k(const unsigned short* __restrict__ qn,
                                              const unsigned short* __restrict__ kbf,
                                              const unsigned short* __restrict__ Wqb,
                                              const unsigned short* __restrict__ Wkvb,
                                              unsigned short* __restrict__ Qw,
                                              unsigned short* __restrict__ Kw,
                                              unsigned short* __restrict__ Vt) {
  __shared__ __align__(16) unsigned short As[128 * 64];
  __shared__ __align__(16) unsigned short Bs[128 * 64];
  const int t = threadIdx.x;
  const int lane = t & 63, wave = t >> 6;
  const int fr = lane & 15, fq = lane >> 4;
  const int wr = (wave >> 1) * 64, wc = (wave & 1) * 64;
  const int blk = blockIdx.x;
  const int which = blk >> 9;          // 0=Q, 1=K, 2=V
  const int lblk = blk & 511;
  const int m0 = (lblk >> 3) * 128, n0 = (lblk & 7) * 128;
  const unsigned short* A = (which == 0) ? qn : kbf;
  const unsigned short* B = (which == 0) ? Wqb
                          : (which == 1) ? Wkvb
                                         : Wkvb + ((size_t)1 << 20);
  const float scale = (which == 0) ? 0.18033688011112f : 1.0f;
  const int lrow = lane >> 3, lcol = (lane & 7) * 8;  // 8 rows x 64 cols per issue
  f32x4 acc[4][4] = {};
  for (int k0 = 0; k0 < DD; k0 += 64) {
    __syncthreads();
#pragma unroll
    for (int i = 0; i < 4; ++i) {
      int rbase = wave * 32 + i * 8;
      int r = rbase + lrow;
      gload_lds16(A + (size_t)(m0 + r) * DD + k0 + lcol, &As[rbase * 64]);
      gload_lds16(B + (size_t)(n0 + r) * DD + k0 + lcol, &Bs[rbase * 64]);
    }
    __syncthreads();
#pragma unroll
    for (int ks = 0; ks < 2; ++ks) {
      bf16x8 af[4], bb[4];
#pragma unroll
      for (int m = 0; m < 4; ++m)
        af[m] = *(const bf16x8*)&As[(wr + m * 16 + fr) * 64 + ks * 32 + fq * 8];
#pragma unroll
      for (int n = 0; n < 4; ++n)
        bb[n] = *(const bf16x8*)&Bs[(wc + n * 16 + fr) * 64 + ks * 32 + fq * 8];
#pragma unroll
      for (int m = 0; m < 4; ++m)
#pragma unroll
        for (int n = 0; n < 4; ++n)
          acc[m][n] = mfma16(af[m], bb[n], acc[m][n]);
    }
  }
  if (which < 2) {
    unsigned short* C = (which == 0) ? Qw : Kw;
#pragma unroll
    for (int m = 0; m < 4; ++m)
#pragma unroll
      for (int n = 0; n < 4; ++n)
#pragma unroll
        for (int i = 0; i < 4; ++i) {
          int r = m0 + wr + m * 16 + fq * 4 + i;
          int c = n0 + wc + n * 16 + fr;
          C[(size_t)r * DD + c] = f2bf(acc[m][n][i] * scale);
        }
  } else {
#pragma unroll
    for (int m = 0; m < 4; ++m)
#pragma unroll
      for (int n = 0; n < 4; ++n)
#pragma unroll
        for (int i = 0; i < 4; ++i) {
          int r = m0 + wr + m * 16 + fq * 4 + i;   // token row = kk*8 + b
          int c = n0 + wc + n * 16 + fr;           // dglob = h*64 + d
          int kk = r >> 3, b_ = r & 7, h_ = c >> 6, d_ = c & 63;
          Vt[(((size_t)(b_ * 16 + h_) * 64 + d_) << 10) + kk] = f2bf(acc[m][n][i]);
        }
  }
}

// ---------------- output GEMM: out = ctx @ Wo^T + residual ----------------
// m97 structure; non-temporal f32 stores (out0 never re-read on device).
__global__ __launch_bounds__(256) void gemm_out_k(const unsigned short* __restrict__ A,
                                                  const unsigned short* __restrict__ B,
                                                  float* __restrict__ C,
                                                  const float* __restrict__ res) {
  __shared__ __align__(16) unsigned short As[128 * 64];
  __shared__ __align__(16) unsigned short Bs[128 * 64];
  const int t = threadIdx.x;
  const int lane = t & 63, wave = t >> 6;
  const int fr = lane & 15, fq = lane >> 4;
  const int wr = (wave >> 1) * 64, wc = (wave & 1) * 64;
  const int m0 = blockIdx.y * 128, n0 = blockIdx.x * 128;
  const int lrow = lane >> 3, lcol = (lane & 7) * 8;
  f32x4 acc[4][4] = {};
  for (int k0 = 0; k0 < DD; k0 += 64) {
    __syncthreads();
#pragma unroll
    for (int i = 0; i < 4; ++i) {
      int rbase = wave * 32 + i * 8;
      int r = rbase + lrow;
      gload_lds16(A + (size_t)(m0 + r) * DD + k0 + lcol, &As[rbase * 64]);
      gload_lds16(B + (size_t)(n0 + r) * DD + k0 + lcol, &Bs[rbase * 64]);
    }
    __syncthreads();
#pragma unroll
    for (int ks = 0; ks < 2; ++ks) {
      bf16x8 af[4], bb[4];
#pragma unroll
      for (int m = 0; m < 4; ++m)
        af[m] = *(const bf16x8*)&As[(wr + m * 16 + fr) * 64 + ks * 32 + fq * 8];
#pragma unroll
      for (int n = 0; n < 4; ++n)
        bb[n] = *(const bf16x8*)&Bs[(wc + n * 16 + fr) * 64 + ks * 32 + fq * 8];
#pragma unroll
      for (int m = 0; m < 4; ++m)
#pragma unroll
        for (int n = 0; n < 4; ++n)
          acc[m][n] = mfma16(af[m], bb[n], acc[m][n]);
    }
  }
#pragma unroll
  for (int m = 0; m < 4; ++m)
#pragma unroll
    for (int n = 0; n < 4; ++n)
#pragma unroll
      for (int i = 0; i < 4; ++i) {
        int r = m0 + wr + m * 16 + fq * 4 + i;
        int c = n0 + wc + n * 16 + fr;
        __builtin_nontemporal_store(acc[m][n][i] + res[(size_t)r * DD + c],
                                    C + (size_t)r * DD + c);
      }
}

// ---------------- fused scores+softmax+PV (two-pass flash) ----------------
// grid: 2048 blocks (1D), 256 threads / 4 waves, QBLK=64 (r16 structure).
// K staging via global_load_lds (async, no VGPR round-trip; linear [128][64]
// LDS, 16-way read conflicts accepted at this 2-barrier regime).
// XCD-aware remap; no max-tracking (log2-domain scores); attn stores
// non-temporal; Ps 64x128 XOR-swizzled.
__global__ __launch_bounds__(256, 2) void attn_fused_k(
    const unsigned short* __restrict__ Q,   // [token][1024], pre-scaled by 0.125*log2e
    const unsigned short* __restrict__ K,   // [token][1024]
    const unsigned short* __restrict__ Vt,  // [(b*16+h)*64 + d][1024 kk]
    const unsigned char* __restrict__ mask,
    float* __restrict__ attn,               // [bh][1024 q][1024 k]
    unsigned short* __restrict__ ctx) {     // [token][1024]
  __shared__ __align__(16) unsigned short KVu[128 * 72];  // K [128][64] linear OR V^T [64][136]
  __shared__ __align__(16) unsigned short Ps[64 * 128];   // P bf16, XOR-swizzled rows
  __shared__ float lrow[64];
  __shared__ float ps2[64][2], maskv[128];

  const int t = threadIdx.x;
  const int lane = t & 63, wave = t >> 6;
  const int fr = lane & 15, fq = lane >> 4;
  // XCD-aware (qt, bh) assignment from linear dispatch id
  const int L = blockIdx.x;                 // 0..2047, dispatch order
  const int xcd = L & 7;
  const int idx = L >> 3;                   // 0..255
  const int bh = xcd * 16 + (idx >> 4);
  const int qt = idx & 15;                  // 16 q-tiles of 64 rows
  const int b = bh >> 4, h = bh & 15;
  const int wrk = (wave >> 1) * 64;   // k-dim strip (S^T rows)
  const int wcq = (wave & 1) * 32;    // q-dim strip (S^T cols), 32 wide
  const int w01 = wave >> 1;
  const int swz = (fr & 7) << 4;      // per-lane Ps byte swizzle (row%8 == fr%8)
  const int lrow2 = lane >> 3, lcol2 = (lane & 7) * 8;  // K stage lane coords

  // Q fragments: loop-invariant, registers (64 q rows)
  bf16x8 qf[2][2];
#pragma unroll
  for (int n = 0; n < 2; ++n)
#pragma unroll
    for (int c = 0; c < 2; ++c)
      qf[n][c] = *(const bf16x8*)(Q +
          (((size_t)(qt * 64 + wcq + n * 16 + fr) * 8 + b) << 10) + h * 64 + c * 32 + fq * 8);

  // ================= pass 1: denominator only (register-resident) =========
  float s_run[2] = {0.0f, 0.0f};
  for (int kt = 0; kt < 8; ++kt) {
    __syncthreads();
    // async K stage: 4 issues/wave, 8 rows each, linear dest
#pragma unroll
    for (int i = 0; i < 4; ++i) {
      int rbase = wave * 32 + i * 8;
      gload_lds16(K + (((size_t)(kt * 128 + rbase + lrow2) * 8 + b) << 10) + h * 64 + lcol2,
                  &KVu[rbase * 64]);
    }
    if (t < 128) maskv[t] = mask[b * 1024 + kt * 128 + t] ? -1.0e9f : 0.0f;
    __syncthreads();   // drains vmcnt -> gload_lds complete
    f32x4 acc[4][2] = {};
#pragma unroll
    for (int k0 = 0; k0 < 2; ++k0) {
      bf16x8 af[4];
#pragma unroll
      for (int m = 0; m < 4; ++m)
        af[m] = *(const bf16x8*)&KVu[(wrk + m * 16 + fr) * 64 + k0 * 32 + fq * 8];
      __builtin_amdgcn_s_setprio(1);
#pragma unroll
      for (int m = 0; m < 4; ++m)
#pragma unroll
        for (int n = 0; n < 2; ++n)
          acc[m][n] = mfma16(af[m], qf[n][k0], acc[m][n]);
      __builtin_amdgcn_s_setprio(0);
    }
    float4 mk[4];
#pragma unroll
    for (int m = 0; m < 4; ++m) mk[m] = *(const float4*)&maskv[wrk + m * 16 + fq * 4];
#pragma unroll
    for (int n = 0; n < 2; ++n) {
      float s = 0.0f;
#pragma unroll
      for (int m = 0; m < 4; ++m) {
        s += __builtin_amdgcn_exp2f(acc[m][n][0] + mk[m].x);
        s += __builtin_amdgcn_exp2f(acc[m][n][1] + mk[m].y);
        s += __builtin_amdgcn_exp2f(acc[m][n][2] + mk[m].z);
        s += __builtin_amdgcn_exp2f(acc[m][n][3] + mk[m].w);
      }
      s_run[n] += s;
    }
  }
  // final cross-lane + cross-wave denominator merge (once)
#pragma unroll
  for (int n = 0; n < 2; ++n) {
    float s = s_run[n];
    s += __shfl_xor(s, 16);
    s += __shfl_xor(s, 32);
    if (fq == 0) ps2[wcq + n * 16 + fr][w01] = s;
  }
  __syncthreads();
  if (t < 64) lrow[t] = 1.0f / (ps2[t][0] + ps2[t][1]);

  // ================= pass 2: P write + attn store + PV =================
  const int wq = (wave >> 1) * 32, wd = (wave & 1) * 32;
  f32x4 accv[2][2] = {};
  for (int kt = 0; kt < 8; ++kt) {
    __syncthreads();
#pragma unroll
    for (int i = 0; i < 4; ++i) {
      int rbase = wave * 32 + i * 8;
      gload_lds16(K + (((size_t)(kt * 128 + rbase + lrow2) * 8 + b) << 10) + h * 64 + lcol2,
                  &KVu[rbase * 64]);
    }
    if (t < 128) maskv[t] = mask[b * 1024 + kt * 128 + t] ? -1.0e9f : 0.0f;
    __syncthreads();   // drains vmcnt -> gload_lds complete
    f32x4 acc[4][2] = {};
#pragma unroll
    for (int k0 = 0; k0 < 2; ++k0) {
      bf16x8 af[4];
#pragma unroll
      for (int m = 0; m < 4; ++m)
        af[m] = *(const bf16x8*)&KVu[(wrk + m * 16 + fr) * 64 + k0 * 32 + fq * 8];
      __builtin_amdgcn_s_setprio(1);
#pragma unroll
      for (int m = 0; m < 4; ++m)
#pragma unroll
        for (int n = 0; n < 2; ++n)
          acc[m][n] = mfma16(af[m], qf[n][k0], acc[m][n]);
      __builtin_amdgcn_s_setprio(0);
    }
    float4 mk[4];
#pragma unroll
    for (int m = 0; m < 4; ++m) mk[m] = *(const float4*)&maskv[wrk + m * 16 + fq * 4];
#pragma unroll
    for (int m = 0; m < 4; ++m)
#pragma unroll
      for (int n = 0; n < 2; ++n) {
        acc[m][n][0] += mk[m].x; acc[m][n][1] += mk[m].y;
        acc[m][n][2] += mk[m].z; acc[m][n][3] += mk[m].w;
      }
    float il[2];
#pragma unroll
    for (int n = 0; n < 2; ++n) il[n] = lrow[wcq + n * 16 + fr];
#pragma unroll
    for (int m = 0; m < 4; ++m) {
      int k4 = wrk + m * 16 + fq * 4;
#pragma unroll
      for (int n = 0; n < 2; ++n) {
        float p0 = __builtin_amdgcn_exp2f(acc[m][n][0]) * il[n];
        float p1 = __builtin_amdgcn_exp2f(acc[m][n][1]) * il[n];
        float p2 = __builtin_amdgcn_exp2f(acc[m][n][2]) * il[n];
        float p3 = __builtin_amdgcn_exp2f(acc[m][n][3]) * il[n];
        uint2 w;
        w.x = f2bf(p0) | ((unsigned)f2bf(p1) << 16);
        w.y = f2bf(p2) | ((unsigned)f2bf(p3) << 16);
        int row = wcq + n * 16 + fr;
        *(uint2*)((char*)Ps + row * 256 + ((k4 * 2) ^ swz)) = w;
      }
    }
    __syncthreads();
    // coalesced attn write (from Ps, non-temporal f32x4) + V^T tile load
#pragma unroll
    for (int it = 0; it < 8; ++it) {
      int idx2 = it * 256 + t;
      int row = idx2 >> 5, colb = (idx2 & 31) << 3;   // 8 bytes per lane
      uint2 d2 = *(const uint2*)((const char*)Ps + row * 256 + (colb ^ ((row & 7) << 4)));
      f32x4 o;
      o[0] = bf2f((unsigned short)(d2.x & 0xFFFF));
      o[1] = bf2f((unsigned short)(d2.x >> 16));
      o[2] = bf2f((unsigned short)(d2.y & 0xFFFF));
      o[3] = bf2f((unsigned short)(d2.y >> 16));
      __builtin_nontemporal_store(
          o, (f32x4*)(attn + ((size_t)bh * 1024 + qt * 64 + row) * 1024 + kt * 128 + (colb >> 1)));
    }
#pragma unroll
    for (int it = 0; it < 4; ++it) {
      int dd = (it * 256 + t) >> 4, k8 = ((it * 256 + t) & 15) << 3;
      *(uint4*)&KVu[dd * 136 + k8] =
          *(const uint4*)(Vt + (((size_t)(b * 16 + h) * 64 + dd) << 10) + kt * 128 + k8);
    }
    __syncthreads();
    // PV: ctx[q][d] += P[q][k] * V[k][d]
#pragma unroll
    for (int ks = 0; ks < 4; ++ks) {
      bf16x8 pa[2], vb[2];
#pragma unroll
      for (int m2 = 0; m2 < 2; ++m2) {
        int row = wq + m2 * 16 + fr;
        pa[m2] = *(const bf16x8*)((const char*)Ps + row * 256 + (((ks * 32 + fq * 8) * 2) ^ swz));
      }
#pragma unroll
      for (int n2 = 0; n2 < 2; ++n2)
        vb[n2] = *(const bf16x8*)&KVu[(wd + n2 * 16 + fr) * 136 + ks * 32 + fq * 8];
      __builtin_amdgcn_s_setprio(1);
#pragma unroll
      for (int m2 = 0; m2 < 2; ++m2)
#pragma unroll
        for (int n2 = 0; n2 < 2; ++n2)
          accv[m2][n2] = mfma16(pa[m2], vb[n2], accv[m2][n2]);
      __builtin_amdgcn_s_setprio(0);
    }
  }
  // ctx epilogue
#pragma unroll
  for (int m2 = 0; m2 < 2; ++m2)
#pragma unroll
    for (int n2 = 0; n2 < 2; ++n2)
#pragma unroll
      for (int i = 0; i < 4; ++i) {
        int qrow = qt * 64 + wq + m2 * 16 + fq * 4 + i;
        int c = h * 64 + wd + n2 * 16 + fr;
        ctx[(((size_t)qrow * 8 + b) << 10) + c] = f2bf(accv[m2][n2][i]);
      }
}

extern "C" void kernel_launch(void* const* d_in, const int* in_sizes, int n_in,
                              void* d_out, int out_size, void* d_ws, size_t ws_size,
                              hipStream_t stream) {
  const float* q = (const float*)d_in[0];
  const float* k = (const float*)d_in[1];
  const unsigned char* mask = (const unsigned char*)d_in[2];
  const float* Wq = (const float*)d_in[3];
  const float* Wkv = (const float*)d_in[4];
  const float* Wo = (const float*)d_in[5];
  const float* ln_g = (const float*)d_in[6];
  const float* ln_b = (const float*)d_in[7];

  float* out0 = (float*)d_out;                   // (1024,8,1024)
  float* attn = out0 + (size_t)LQ * BB * DD;     // (8,16,1024,1024)

  char* ws = (char*)d_ws;
  unsigned short* qn   = (unsigned short*)(ws);                        // 16 MB
  unsigned short* kbf  = (unsigned short*)(ws + ((size_t)16 << 20));   // 16 MB
  unsigned short* Qw   = (unsigned short*)(ws + ((size_t)32 << 20));   // 16 MB
  unsigned short* ctxw = (unsigned short*)(ws + ((size_t)48 << 20));   // 16 MB
  unsigned short* Kw   = (unsigned short*)(ws + ((size_t)64 << 20));   // 16 MB
  unsigned short* Vtg  = (unsigned short*)(ws + ((size_t)80 << 20));   // 16 MB
  unsigned short* Wqb  = (unsigned short*)(ws + ((size_t)96 << 20));   // 2 MB
  unsigned short* Wkvb = (unsigned short*)(ws + ((size_t)98 << 20));   // 4 MB
  unsigned short* Wob  = (unsigned short*)(ws + ((size_t)102 << 20));  // 2 MB

  // fused prologue: k cvt + weight cvts + layernorm in one launch
  prologue_k<<<20480, 256, 0, stream>>>(k, kbf, Wq, Wkv, Wo, Wqb, Wkvb, Wob,
                                        q, ln_g, ln_b, qn);

  // fused projections: Q (log2e-scaled) | K | V^T in one launch
  proj_k<<<1536, 256, 0, stream>>>(qn, kbf, Wqb, Wkvb, Qw, Kw, Vtg);

  // fused scores+softmax+PV  (1D grid, 2048 blocks, XCD-aware remap)
  attn_fused_k<<<dim3(16 * BB * HH), 256, 0, stream>>>(Qw, Kw, Vtg, mask, attn, ctxw);

  // out = ctx @ Wo^T + residual
  gemm_out_k<<<dim3(8, 64), 256, 0, stream>>>(ctxw, Wob, out0, q);
}

// Round 22
// 275.250 us; speedup vs baseline: 1.1761x; 1.0002x over previous
//
#include <hip/hip_runtime.h>
#include <stdint.h>

typedef __bf16 bf16x8 __attribute__((ext_vector_type(8)));
typedef float f32x4 __attribute__((ext_vector_type(4)));

#define LQ 1024
#define LK 1024
#define BB 8
#define DD 1024
#define HH 16
#define DK 64

__device__ __forceinline__ unsigned short f2bf(float f) {
  union { float f; unsigned u; } v; v.f = f;
  unsigned u = v.u;
  u += 0x7FFFu + ((u >> 16) & 1u);   // RNE
  return (unsigned short)(u >> 16);
}
__device__ __forceinline__ float bf2f(unsigned short u) {
  union { unsigned u; float f; } v; v.u = ((unsigned)u) << 16;
  return v.f;
}
__device__ __forceinline__ f32x4 mfma16(bf16x8 a, bf16x8 b, f32x4 c) {
  return __builtin_amdgcn_mfma_f32_16x16x32_bf16(a, b, c, 0, 0, 0);
}
// async global->LDS, 16B per lane; LDS dest is wave-uniform base + lane*16
__device__ __forceinline__ void gload_lds16(const unsigned short* g, unsigned short* l) {
  __builtin_amdgcn_global_load_lds(
      (const __attribute__((address_space(1))) void*)g,
      (__attribute__((address_space(3))) void*)l, 16, 0, 0);
}

// ------ fused prologue: k->bf16 | weight cvts | layernorm, ONE launch -----
// blocks [0,8192): cvt k (2M float4)
// blocks [8192,12288): cvt Wq|Wkv|Wo (1M float4)
// blocks [12288,20480): layernorm rows (8192 rows)
__global__ __launch_bounds__(256) void prologue_k(
    const float* __restrict__ kin, unsigned short* __restrict__ kbf,
    const float* __restrict__ Wq, const float* __restrict__ Wkv,
    const float* __restrict__ Wo, unsigned short* __restrict__ oq,
    unsigned short* __restrict__ okv, unsigned short* __restrict__ oo,
    const float* __restrict__ x, const float* __restrict__ g,
    const float* __restrict__ bta, unsigned short* __restrict__ xout) {
  const int blk = blockIdx.x;
  const int t = threadIdx.x;
  if (blk < 8192) {
    // ---- cvt k ----
    int i = blk * 256 + t;
    float4 v = *(const float4*)(kin + (size_t)i * 4);
    uint2 o;
    o.x = f2bf(v.x) | ((unsigned)f2bf(v.y) << 16);
    o.y = f2bf(v.z) | ((unsigned)f2bf(v.w) << 16);
    *(uint2*)(kbf + (size_t)i * 4) = o;
  } else if (blk < 12288) {
    // ---- cvt weights ----
    int i = (blk - 8192) * 256 + t;   // 0..1M float4
    const float* in;
    unsigned short* out;
    int j;
    if (i < 262144) { in = Wq; out = oq; j = i; }
    else if (i < 786432) { in = Wkv; out = okv; j = i - 262144; }
    else { in = Wo; out = oo; j = i - 786432; }
    float4 v = *(const float4*)(in + (size_t)j * 4);
    uint2 o;
    o.x = f2bf(v.x) | ((unsigned)f2bf(v.y) << 16);
    o.y = f2bf(v.z) | ((unsigned)f2bf(v.w) << 16);
    *(uint2*)(out + (size_t)j * 4) = o;
  } else {
    // ---- layernorm ----
    const int row = blk - 12288;
    const float* xr = x + (size_t)row * DD;
    float4 v = *(const float4*)(xr + t * 4);
    float s = v.x + v.y + v.z + v.w;
    float s2 = v.x * v.x + v.y * v.y + v.z * v.z + v.w * v.w;
    for (int off = 32; off > 0; off >>= 1) {
      s += __shfl_down(s, off);
      s2 += __shfl_down(s2, off);
    }
    __shared__ float red[8];
    int lane = t & 63, w = t >> 6;
    if (lane == 0) { red[w] = s; red[4 + w] = s2; }
    __syncthreads();
    s = red[0] + red[1] + red[2] + red[3];
    s2 = red[4] + red[5] + red[6] + red[7];
    float mu = s * (1.0f / 1024.0f);
    float var = s2 * (1.0f / 1024.0f) - mu * mu;
    float inv = rsqrtf(var + 1e-5f);
    float4 gv = *(const float4*)(g + t * 4);
    float4 bv = *(const float4*)(bta + t * 4);
    uint2 o;
    o.x = f2bf((v.x - mu) * inv * gv.x + bv.x) |
          ((unsigned)f2bf((v.y - mu) * inv * gv.y + bv.y) << 16);
    o.y = f2bf((v.z - mu) * inv * gv.z + bv.z) |
          ((unsigned)f2bf((v.w - mu) * inv * gv.w + bv.w) << 16);
    *(uint2*)(xout + (size_t)row * DD + t * 4) = o;
  }
}

// ------- fused projection GEMMs: Q | K | V^T in ONE 1536-block launch -----
// blocks [0,512):    Qw  = qn  @ Wq^T * (0.125*log2e)   (bf16 out)
// blocks [512,1024): Kw  = kbf @ Wk^T                   (bf16 out)
// blocks [1024,1536): Vt = transpose-scatter(kbf @ Wv^T)
// m97 structure: BK=64, global_load_lds width-16 staging, linear LDS tiles.
__global__ __launch_bounds__(256) void proj_k(const unsigned short* __restrict__ qn,
                                              const unsigned short* __restrict__ kbf,
                                              const unsigned short* __restrict__ Wqb,
                                              const unsigned short* __restrict__ Wkvb,
                                              unsigned short* __restrict__ Qw,
                                              unsigned short* __restrict__ Kw,
                                              unsigned short* __restrict__ Vt) {
  __shared__ __align__(16) unsigned short As[128 * 64];
  __shared__ __align__(16) unsigned short Bs[128 * 64];
  const int t = threadIdx.x;
  const int lane = t & 63, wave = t >> 6;
  const int fr = lane & 15, fq = lane >> 4;
  const int wr = (wave >> 1) * 64, wc = (wave & 1) * 64;
  const int blk = blockIdx.x;
  const int which = blk >> 9;          // 0=Q, 1=K, 2=V
  const int lblk = blk & 511;
  const int m0 = (lblk >> 3) * 128, n0 = (lblk & 7) * 128;
  const unsigned short* A = (which == 0) ? qn : kbf;
  const unsigned short* B = (which == 0) ? Wqb
                          : (which == 1) ? Wkvb
                                         : Wkvb + ((size_t)1 << 20);
  const float scale = (which == 0) ? 0.18033688011112f : 1.0f;
  const int lrow = lane >> 3, lcol = (lane & 7) * 8;  // 8 rows x 64 cols per issue
  f32x4 acc[4][4] = {};
  for (int k0 = 0; k0 < DD; k0 += 64) {
    __syncthreads();
#pragma unroll
    for (int i = 0; i < 4; ++i) {
      int rbase = wave * 32 + i * 8;
      int r = rbase + lrow;
      gload_lds16(A + (size_t)(m0 + r) * DD + k0 + lcol, &As[rbase * 64]);
      gload_lds16(B + (size_t)(n0 + r) * DD + k0 + lcol, &Bs[rbase * 64]);
    }
    __syncthreads();
#pragma unroll
    for (int ks = 0; ks < 2; ++ks) {
      bf16x8 af[4], bb[4];
#pragma unroll
      for (int m = 0; m < 4; ++m)
        af[m] = *(const bf16x8*)&As[(wr + m * 16 + fr) * 64 + ks * 32 + fq * 8];
#pragma unroll
      for (int n = 0; n < 4; ++n)
        bb[n] = *(const bf16x8*)&Bs[(wc + n * 16 + fr) * 64 + ks * 32 + fq * 8];
#pragma unroll
      for (int m = 0; m < 4; ++m)
#pragma unroll
        for (int n = 0; n < 4; ++n)
          acc[m][n] = mfma16(af[m], bb[n], acc[m][n]);
    }
  }
  if (which < 2) {
    unsigned short* C = (which == 0) ? Qw : Kw;
#pragma unroll
    for (int m = 0; m < 4; ++m)
#pragma unroll
      for (int n = 0; n < 4; ++n)
#pragma unroll
        for (int i = 0; i < 4; ++i) {
          int r = m0 + wr + m * 16 + fq * 4 + i;
          int c = n0 + wc + n * 16 + fr;
          C[(size_t)r * DD + c] = f2bf(acc[m][n][i] * scale);
        }
  } else {
#pragma unroll
    for (int m = 0; m < 4; ++m)
#pragma unroll
      for (int n = 0; n < 4; ++n)
#pragma unroll
        for (int i = 0; i < 4; ++i) {
          int r = m0 + wr + m * 16 + fq * 4 + i;   // token row = kk*8 + b
          int c = n0 + wc + n * 16 + fr;           // dglob = h*64 + d
          int kk = r >> 3, b_ = r & 7, h_ = c >> 6, d_ = c & 63;
          Vt[(((size_t)(b_ * 16 + h_) * 64 + d_) << 10) + kk] = f2bf(acc[m][n][i]);
        }
  }
}

// ---------------- output GEMM: out = ctx @ Wo^T + residual ----------------
// m97 structure; non-temporal f32 stores (out0 never re-read on device).
__global__ __launch_bounds__(256) void gemm_out_k(const unsigned short* __restrict__ A,
                                                  const unsigned short* __restrict__ B,
                                                  float* __restrict__ C,
                                                  const float* __restrict__ res) {
  __shared__ __align__(16) unsigned short As[128 * 64];
  __shared__ __align__(16) unsigned short Bs[128 * 64];
  const int t = threadIdx.x;
  const int lane = t & 63, wave = t >> 6;
  const int fr = lane & 15, fq = lane >> 4;
  const int wr = (wave >> 1) * 64, wc = (wave & 1) * 64;
  const int m0 = blockIdx.y * 128, n0 = blockIdx.x * 128;
  const int lrow = lane >> 3, lcol = (lane & 7) * 8;
  f32x4 acc[4][4] = {};
  for (int k0 = 0; k0 < DD; k0 += 64) {
    __syncthreads();
#pragma unroll
    for (int i = 0; i < 4; ++i) {
      int rbase = wave * 32 + i * 8;
      int r = rbase + lrow;
      gload_lds16(A + (size_t)(m0 + r) * DD + k0 + lcol, &As[rbase * 64]);
      gload_lds16(B + (size_t)(n0 + r) * DD + k0 + lcol, &Bs[rbase * 64]);
    }
    __syncthreads();
#pragma unroll
    for (int ks = 0; ks < 2; ++ks) {
      bf16x8 af[4], bb[4];
#pragma unroll
      for (int m = 0; m < 4; ++m)
        af[m] = *(const bf16x8*)&As[(wr + m * 16 + fr) * 64 + ks * 32 + fq * 8];
#pragma unroll
      for (int n = 0; n < 4; ++n)
        bb[n] = *(const bf16x8*)&Bs[(wc + n * 16 + fr) * 64 + ks * 32 + fq * 8];
#pragma unroll
      for (int m = 0; m < 4; ++m)
#pragma unroll
        for (int n = 0; n < 4; ++n)
          acc[m][n] = mfma16(af[m], bb[n], acc[m][n]);
    }
  }
#pragma unroll
  for (int m = 0; m < 4; ++m)
#pragma unroll
    for (int n = 0; n < 4; ++n)
#pragma unroll
      for (int i = 0; i < 4; ++i) {
        int r = m0 + wr + m * 16 + fq * 4 + i;
        int c = n0 + wc + n * 16 + fr;
        __builtin_nontemporal_store(acc[m][n][i] + res[(size_t)r * DD + c],
                                    C + (size_t)r * DD + c);
      }
}

// ---------------- fused scores+softmax+PV (two-pass flash) ----------------
// grid: 2048 blocks (1D), 256 threads / 4 waves, QBLK=64 (r16 structure).
// __launch_bounds__(256,3): VGPR budget 168; QBLK=64 live state ~130 so no
// spill expected -> 3 waves/SIMD (r9's spill was QBLK=128 state at cap 84).
// K staging via global_load_lds; XCD-aware remap; no max-tracking; attn
// stores non-temporal; Ps 64x128 XOR-swizzled.
__global__ __launch_bounds__(256, 3) void attn_fused_k(
    const unsigned short* __restrict__ Q,   // [token][1024], pre-scaled by 0.125*log2e
    const unsigned short* __restrict__ K,   // [token][1024]
    const unsigned short* __restrict__ Vt,  // [(b*16+h)*64 + d][1024 kk]
    const unsigned char* __restrict__ mask,
    float* __restrict__ attn,               // [bh][1024 q][1024 k]
    unsigned short* __restrict__ ctx) {     // [token][1024]
  __shared__ __align__(16) unsigned short KVu[128 * 72];  // K [128][64] linear OR V^T [64][136]
  __shared__ __align__(16) unsigned short Ps[64 * 128];   // P bf16, XOR-swizzled rows
  __shared__ float lrow[64];
  __shared__ float ps2[64][2], maskv[128];

  const int t = threadIdx.x;
  const int lane = t & 63, wave = t >> 6;
  const int fr = lane & 15, fq = lane >> 4;
  // XCD-aware (qt, bh) assignment from linear dispatch id
  const int L = blockIdx.x;                 // 0..2047, dispatch order
  const int xcd = L & 7;
  const int idx = L >> 3;                   // 0..255
  const int bh = xcd * 16 + (idx >> 4);
  const int qt = idx & 15;                  // 16 q-tiles of 64 rows
  const int b = bh >> 4, h = bh & 15;
  const int wrk = (wave >> 1) * 64;   // k-dim strip (S^T rows)
  const int wcq = (wave & 1) * 32;    // q-dim strip (S^T cols), 32 wide
  const int w01 = wave >> 1;
  const int swz = (fr & 7) << 4;      // per-lane Ps byte swizzle (row%8 == fr%8)
  const int lrow2 = lane >> 3, lcol2 = (lane & 7) * 8;  // K stage lane coords

  // Q fragments: loop-invariant, registers (64 q rows)
  bf16x8 qf[2][2];
#pragma unroll
  for (int n = 0; n < 2; ++n)
#pragma unroll
    for (int c = 0; c < 2; ++c)
      qf[n][c] = *(const bf16x8*)(Q +
          (((size_t)(qt * 64 + wcq + n * 16 + fr) * 8 + b) << 10) + h * 64 + c * 32 + fq * 8);

  // ================= pass 1: denominator only (register-resident) =========
  float s_run[2] = {0.0f, 0.0f};
  for (int kt = 0; kt < 8; ++kt) {
    __syncthreads();
    // async K stage: 4 issues/wave, 8 rows each, linear dest
#pragma unroll
    for (int i = 0; i < 4; ++i) {
      int rbase = wave * 32 + i * 8;
      gload_lds16(K + (((size_t)(kt * 128 + rbase + lrow2) * 8 + b) << 10) + h * 64 + lcol2,
                  &KVu[rbase * 64]);
    }
    if (t < 128) maskv[t] = mask[b * 1024 + kt * 128 + t] ? -1.0e9f : 0.0f;
    __syncthreads();   // drains vmcnt -> gload_lds complete
    f32x4 acc[4][2] = {};
#pragma unroll
    for (int k0 = 0; k0 < 2; ++k0) {
      bf16x8 af[4];
#pragma unroll
      for (int m = 0; m < 4; ++m)
        af[m] = *(const bf16x8*)&KVu[(wrk + m * 16 + fr) * 64 + k0 * 32 + fq * 8];
      __builtin_amdgcn_s_setprio(1);
#pragma unroll
      for (int m = 0; m < 4; ++m)
#pragma unroll
        for (int n = 0; n < 2; ++n)
          acc[m][n] = mfma16(af[m], qf[n][k0], acc[m][n]);
      __builtin_amdgcn_s_setprio(0);
    }
    float4 mk[4];
#pragma unroll
    for (int m = 0; m < 4; ++m) mk[m] = *(const float4*)&maskv[wrk + m * 16 + fq * 4];
#pragma unroll
    for (int n = 0; n < 2; ++n) {
      float s = 0.0f;
#pragma unroll
      for (int m = 0; m < 4; ++m) {
        s += __builtin_amdgcn_exp2f(acc[m][n][0] + mk[m].x);
        s += __builtin_amdgcn_exp2f(acc[m][n][1] + mk[m].y);
        s += __builtin_amdgcn_exp2f(acc[m][n][2] + mk[m].z);
        s += __builtin_amdgcn_exp2f(acc[m][n][3] + mk[m].w);
      }
      s_run[n] += s;
    }
  }
  // final cross-lane + cross-wave denominator merge (once)
#pragma unroll
  for (int n = 0; n < 2; ++n) {
    float s = s_run[n];
    s += __shfl_xor(s, 16);
    s += __shfl_xor(s, 32);
    if (fq == 0) ps2[wcq + n * 16 + fr][w01] = s;
  }
  __syncthreads();
  if (t < 64) lrow[t] = 1.0f / (ps2[t][0] + ps2[t][1]);

  // ================= pass 2: P write + attn store + PV =================
  const int wq = (wave >> 1) * 32, wd = (wave & 1) * 32;
  f32x4 accv[2][2] = {};
  for (int kt = 0; kt < 8; ++kt) {
    __syncthreads();
#pragma unroll
    for (int i = 0; i < 4; ++i) {
      int rbase = wave * 32 + i * 8;
      gload_lds16(K + (((size_t)(kt * 128 + rbase + lrow2) * 8 + b) << 10) + h * 64 + lcol2,
                  &KVu[rbase * 64]);
    }
    if (t < 128) maskv[t] = mask[b * 1024 + kt * 128 + t] ? -1.0e9f : 0.0f;
    __syncthreads();   // drains vmcnt -> gload_lds complete
    f32x4 acc[4][2] = {};
#pragma unroll
    for (int k0 = 0; k0 < 2; ++k0) {
      bf16x8 af[4];
#pragma unroll
      for (int m = 0; m < 4; ++m)
        af[m] = *(const bf16x8*)&KVu[(wrk + m * 16 + fr) * 64 + k0 * 32 + fq * 8];
      __builtin_amdgcn_s_setprio(1);
#pragma unroll
      for (int m = 0; m < 4; ++m)
#pragma unroll
        for (int n = 0; n < 2; ++n)
          acc[m][n] = mfma16(af[m], qf[n][k0], acc[m][n]);
      __builtin_amdgcn_s_setprio(0);
    }
    float4 mk[4];
#pragma unroll
    for (int m = 0; m < 4; ++m) mk[m] = *(const float4*)&maskv[wrk + m * 16 + fq * 4];
#pragma unroll
    for (int m = 0; m < 4; ++m)
#pragma unroll
      for (int n = 0; n < 2; ++n) {
        acc[m][n][0] += mk[m].x; acc[m][n][1] += mk[m].y;
        acc[m][n][2] += mk[m].z; acc[m][n][3] += mk[m].w;
      }
    float il[2];
#pragma unroll
    for (int n = 0; n < 2; ++n) il[n] = lrow[wcq + n * 16 + fr];
#pragma unroll
    for (int m = 0; m < 4; ++m) {
      int k4 = wrk + m * 16 + fq * 4;
#pragma unroll
      for (int n = 0; n < 2; ++n) {
        float p0 = __builtin_amdgcn_exp2f(acc[m][n][0]) * il[n];
        float p1 = __builtin_amdgcn_exp2f(acc[m][n][1]) * il[n];
        float p2 = __builtin_amdgcn_exp2f(acc[m][n][2]) * il[n];
        float p3 = __builtin_amdgcn_exp2f(acc[m][n][3]) * il[n];
        uint2 w;
        w.x = f2bf(p0) | ((unsigned)f2bf(p1) << 16);
        w.y = f2bf(p2) | ((unsigned)f2bf(p3) << 16);
        int row = wcq + n * 16 + fr;
        *(uint2*)((char*)Ps + row * 256 + ((k4 * 2) ^ swz)) = w;
      }
    }
    __syncthreads();
    // coalesced attn write (from Ps, non-temporal f32x4) + V^T tile load
#pragma unroll
    for (int it = 0; it < 8; ++it) {
      int idx2 = it * 256 + t;
      int row = idx2 >> 5, colb = (idx2 & 31) << 3;   // 8 bytes per lane
      uint2 d2 = *(const uint2*)((const char*)Ps + row * 256 + (colb ^ ((row & 7) << 4)));
      f32x4 o;
      o[0] = bf2f((unsigned short)(d2.x & 0xFFFF));
      o[1] = bf2f((unsigned short)(d2.x >> 16));
      o[2] = bf2f((unsigned short)(d2.y & 0xFFFF));
      o[3] = bf2f((unsigned short)(d2.y >> 16));
      __builtin_nontemporal_store(
          o, (f32x4*)(attn + ((size_t)bh * 1024 + qt * 64 + row) * 1024 + kt * 128 + (colb >> 1)));
    }
#pragma unroll
    for (int it = 0; it < 4; ++it) {
      int dd = (it * 256 + t) >> 4, k8 = ((it * 256 + t) & 15) << 3;
      *(uint4*)&KVu[dd * 136 + k8] =
          *(const uint4*)(Vt + (((size_t)(b * 16 + h) * 64 + dd) << 10) + kt * 128 + k8);
    }
    __syncthreads();
    // PV: ctx[q][d] += P[q][k] * V[k][d]
#pragma unroll
    for (int ks = 0; ks < 4; ++ks) {
      bf16x8 pa[2], vb[2];
#pragma unroll
      for (int m2 = 0; m2 < 2; ++m2) {
        int row = wq + m2 * 16 + fr;
        pa[m2] = *(const bf16x8*)((const char*)Ps + row * 256 + (((ks * 32 + fq * 8) * 2) ^ swz));
      }
#pragma unroll
      for (int n2 = 0; n2 < 2; ++n2)
        vb[n2] = *(const bf16x8*)&KVu[(wd + n2 * 16 + fr) * 136 + ks * 32 + fq * 8];
      __builtin_amdgcn_s_setprio(1);
#pragma unroll
      for (int m2 = 0; m2 < 2; ++m2)
#pragma unroll
        for (int n2 = 0; n2 < 2; ++n2)
          accv[m2][n2] = mfma16(pa[m2], vb[n2], accv[m2][n2]);
      __builtin_amdgcn_s_setprio(0);
    }
  }
  // ctx epilogue
#pragma unroll
  for (int m2 = 0; m2 < 2; ++m2)
#pragma unroll
    for (int n2 = 0; n2 < 2; ++n2)
#pragma unroll
      for (int i = 0; i < 4; ++i) {
        int qrow = qt * 64 + wq + m2 * 16 + fq * 4 + i;
        int c = h * 64 + wd + n2 * 16 + fr;
        ctx[(((size_t)qrow * 8 + b) << 10) + c] = f2bf(accv[m2][n2][i]);
      }
}

extern "C" void kernel_launch(void* const* d_in, const int* in_sizes, int n_in,
                              void* d_out, int out_size, void* d_ws, size_t ws_size,
                              hipStream_t stream) {
  const float* q = (const float*)d_in[0];
  const float* k = (const float*)d_in[1];
  const unsigned char* mask = (const unsigned char*)d_in[2];
  const float* Wq = (const float*)d_in[3];
  const float* Wkv = (const float*)d_in[4];
  const float* Wo = (const float*)d_in[5];
  const float* ln_g = (const float*)d_in[6];
  const float* ln_b = (const float*)d_in[7];

  float* out0 = (float*)d_out;                   // (1024,8,1024)
  float* attn = out0 + (size_t)LQ * BB * DD;     // (8,16,1024,1024)

  char* ws = (char*)d_ws;
  unsigned short* qn   = (unsigned short*)(ws);                        // 16 MB
  unsigned short* kbf  = (unsigned short*)(ws + ((size_t)16 << 20));   // 16 MB
  unsigned short* Qw   = (unsigned short*)(ws + ((size_t)32 << 20));   // 16 MB
  unsigned short* ctxw = (unsigned short*)(ws + ((size_t)48 << 20));   // 16 MB
  unsigned short* Kw   = (unsigned short*)(ws + ((size_t)64 << 20));   // 16 MB
  unsigned short* Vtg  = (unsigned short*)(ws + ((size_t)80 << 20));   // 16 MB
  unsigned short* Wqb  = (unsigned short*)(ws + ((size_t)96 << 20));   // 2 MB
  unsigned short* Wkvb = (unsigned short*)(ws + ((size_t)98 << 20));   // 4 MB
  unsigned short* Wob  = (unsigned short*)(ws + ((size_t)102 << 20));  // 2 MB

  // fused prologue: k cvt + weight cvts + layernorm in one launch
  prologue_k<<<20480, 256, 0, stream>>>(k, kbf, Wq, Wkv, Wo, Wqb, Wkvb, Wob,
                                        q, ln_g, ln_b, qn);

  // fused projections: Q (log2e-scaled) | K | V^T in one launch
  proj_k<<<1536, 256, 0, stream>>>(qn, kbf, Wqb, Wkvb, Qw, Kw, Vtg);

  // fused scores+softmax+PV  (1D grid, 2048 blocks, XCD-aware remap)
  attn_fused_k<<<dim3(16 * BB * HH), 256, 0, stream>>>(Qw, Kw, Vtg, mask, attn, ctxw);

  // out = ctx @ Wo^T + residual
  gemm_out_k<<<dim3(8, 64), 256, 0, stream>>>(ctxw, Wob, out0, q);
}